// Round 18
// baseline (276.152 us; speedup 1.0000x reference)
//
#include <hip/hip_runtime.h>
#include <hip/hip_bf16.h>
#include <math.h>

#define BB 2
#define SS 2048
#define EE 2048
#define HH 16
#define DD 128
#define MM (BB*SS)

typedef __attribute__((ext_vector_type(8))) short bf16x8;
typedef __attribute__((ext_vector_type(4))) float f32x4;
typedef __attribute__((ext_vector_type(16))) float f32x16;
typedef __attribute__((ext_vector_type(4))) unsigned u32x4;

__device__ inline float bf2f(const __hip_bfloat16 h){ return __bfloat162float(h); }
__device__ inline __hip_bfloat16 f2bf(float f){ return __float2bfloat16(f); }
__device__ inline short f2bs(float f){
  union { __hip_bfloat16 h; short s; } u; u.h = __float2bfloat16(f); return u.s;
}
__device__ inline unsigned pk2(float a, float b){
  union { __hip_bfloat162 h2; unsigned u; } x;
  x.h2 = __float22bfloat162_rn(float2{a,b}); return x.u;   // low half = a
}

__device__ inline void gload16(const void* g, void* l){
  __builtin_amdgcn_global_load_lds((const __attribute__((address_space(1))) void*)g,
      (__attribute__((address_space(3))) void*)l, 16, 0, 0);
}

// 1/sqrt(128) * log2(e): folded into Q during its GEMM-epilogue RoPE
#define QSCL 0.12754614533018515f

// ---------------- fp32 -> bf16 convert, 5 tensors in one launch ----------------
struct P5 { const float* s0; const float* s1; const float* s2; const float* s3; const float* s4;
            __hip_bfloat16* d0; __hip_bfloat16* d1; __hip_bfloat16* d2; __hip_bfloat16* d3; __hip_bfloat16* d4;
            int n0; int n1; };
__global__ void cvt5_kernel(P5 p){
  int w = blockIdx.y;
  const float* in = w==0 ? p.s0 : w==1 ? p.s1 : w==2 ? p.s2 : w==3 ? p.s3 : p.s4;
  __hip_bfloat16* out = w==0 ? p.d0 : w==1 ? p.d1 : w==2 ? p.d2 : w==3 ? p.d3 : p.d4;
  int n4 = w==0 ? p.n0 : p.n1;
  int i = blockIdx.x*256 + threadIdx.x;
  if (i >= n4) return;
  float4 v = ((const float4*)in)[i];
  union { short4 s4; short s[4]; } u;
  u.s[0] = f2bs(v.x); u.s[1] = f2bs(v.y); u.s[2] = f2bs(v.z); u.s[3] = f2bs(v.w);
  ((short4*)out)[i] = u.s4;
}

// ---------------- RoPE tables ----------------
__global__ void rope_tables_kernel(float* __restrict__ cost, float* __restrict__ sint){
  int idx = blockIdx.x*256 + threadIdx.x;  // SS*64
  int s = idx >> 6, i = idx & 63;
  double inv = exp(-log(10000.0) * (double)i / 64.0);
  double f = (double)s * inv;
  cost[idx] = (float)cos(f);
  sint[idx] = (float)sin(f);
}

// ---------------- bf16 GEMM, 128x256 tile, BK=64, 8 waves, 4-phase pipeline (R16) ----------------
// MODE 0: bf16 C; MODE 1: bf16 vt; MODE 2: fp32 C; MODE 3: bf16+RoPE+QSCL (q); MODE 4: bf16+RoPE (k)
template<int MODE>
__global__ __launch_bounds__(512) void gemm256(const __hip_bfloat16* __restrict__ A,
        const __hip_bfloat16* __restrict__ Bw, const float* __restrict__ bias,
        void* __restrict__ Cout,
        const float* __restrict__ cost, const float* __restrict__ sint){
  __shared__ __align__(1024) char lds[147456];
  const int tid = threadIdx.x, wid = tid>>6, lane = tid&63, g = lane>>4, c16 = lane&15;
  const int wm = wid>>2, wn = wid&3;
  const int orig = blockIdx.x;
  const int wg = (orig & 7)*32 + (orig >> 3);
  const int bm = wg & 31, bn = wg >> 5;
  const int rowA0 = bm*128, rowB0 = bn*256;
  const char* Ab8 = (const char*)A + (size_t)rowA0*4096;
  const char* Bb8 = (const char*)Bw + (size_t)rowB0*4096;

  f32x4 acc[4][4] = {};

  auto stageA = [&](int t, char* buf, int i){
    int off = i*8192 + tid*16;
    int r = off >> 7;
    int cs = (off & 127) ^ ((r&7)<<4);
    gload16(Ab8 + (size_t)r*4096 + t*128 + cs, buf + i*8192 + wid*1024);
  };
  auto stageB = [&](int t, char* buf, int i){
    int off = i*8192 + tid*16;
    int r = off >> 7;
    int cs = (off & 127) ^ ((r&7)<<4);
    gload16(Bb8 + (size_t)r*4096 + t*128 + cs, buf + 16384 + i*8192 + wid*1024);
  };

  char* b0 = lds;
  char* b1 = lds + 49152;
  char* b2 = lds + 98304;

  stageA(0,b0,0); stageA(0,b0,1);
  stageB(0,b0,0); stageB(0,b0,1); stageB(0,b0,2); stageB(0,b0,3);
  stageA(1,b1,0); stageA(1,b1,1);
  stageB(1,b1,0); stageB(1,b1,1); stageB(1,b1,2); stageB(1,b1,3);
  asm volatile("s_waitcnt vmcnt(6)" ::: "memory");
  asm volatile("s_barrier" ::: "memory");

  const int rB[4] = { wn*64 + 0*16 + c16, wn*64 + 1*16 + c16, wn*64 + 2*16 + c16, wn*64 + 3*16 + c16 };
  const int rA[4] = { wm*64 + 0*16 + c16, wm*64 + 1*16 + c16, wm*64 + 2*16 + c16, wm*64 + 3*16 + c16 };

  #pragma unroll 1
  for (int t = 0; t < 32; ++t){
    const char* Abuf = b0;
    const char* Bbuf = b0 + 16384;
    const bool st = (t + 2 < 32);
    bf16x8 bfr[4];

    {
      #pragma unroll
      for (int ni=0;ni<4;ni++)
        bfr[ni] = *(const bf16x8*)(Bbuf + rB[ni]*128 + ((g*16) ^ ((rB[ni]&7)<<4)));
      bf16x8 a0 = *(const bf16x8*)(Abuf + rA[0]*128 + ((g*16) ^ ((rA[0]&7)<<4)));
      bf16x8 a1 = *(const bf16x8*)(Abuf + rA[1]*128 + ((g*16) ^ ((rA[1]&7)<<4)));
      if (st){ stageA(t+2,b2,0); stageA(t+2,b2,1); }
      asm volatile("s_barrier" ::: "memory");
      __builtin_amdgcn_s_setprio(1);
      #pragma unroll
      for (int ni=0;ni<4;ni++){
        acc[0][ni] = __builtin_amdgcn_mfma_f32_16x16x32_bf16(a0, bfr[ni], acc[0][ni],0,0,0);
        acc[1][ni] = __builtin_amdgcn_mfma_f32_16x16x32_bf16(a1, bfr[ni], acc[1][ni],0,0,0);
      }
      __builtin_amdgcn_s_setprio(0);
      asm volatile("s_barrier" ::: "memory");
    }
    {
      bf16x8 a2 = *(const bf16x8*)(Abuf + rA[2]*128 + ((g*16) ^ ((rA[2]&7)<<4)));
      bf16x8 a3 = *(const bf16x8*)(Abuf + rA[3]*128 + ((g*16) ^ ((rA[3]&7)<<4)));
      if (st){ stageB(t+2,b2,0); stageB(t+2,b2,1); }
      asm volatile("s_barrier" ::: "memory");
      __builtin_amdgcn_s_setprio(1);
      #pragma unroll
      for (int ni=0;ni<4;ni++){
        acc[2][ni] = __builtin_amdgcn_mfma_f32_16x16x32_bf16(a2, bfr[ni], acc[2][ni],0,0,0);
        acc[3][ni] = __builtin_amdgcn_mfma_f32_16x16x32_bf16(a3, bfr[ni], acc[3][ni],0,0,0);
      }
      __builtin_amdgcn_s_setprio(0);
      asm volatile("s_barrier" ::: "memory");
    }
    {
      #pragma unroll
      for (int ni=0;ni<4;ni++)
        bfr[ni] = *(const bf16x8*)(Bbuf + rB[ni]*128 + ((64 + g*16) ^ ((rB[ni]&7)<<4)));
      bf16x8 a0 = *(const bf16x8*)(Abuf + rA[0]*128 + ((64 + g*16) ^ ((rA[0]&7)<<4)));
      bf16x8 a1 = *(const bf16x8*)(Abuf + rA[1]*128 + ((64 + g*16) ^ ((rA[1]&7)<<4)));
      if (st){ stageB(t+2,b2,2); }
      asm volatile("s_barrier" ::: "memory");
      __builtin_amdgcn_s_setprio(1);
      #pragma unroll
      for (int ni=0;ni<4;ni++){
        acc[0][ni] = __builtin_amdgcn_mfma_f32_16x16x32_bf16(a0, bfr[ni], acc[0][ni],0,0,0);
        acc[1][ni] = __builtin_amdgcn_mfma_f32_16x16x32_bf16(a1, bfr[ni], acc[1][ni],0,0,0);
      }
      __builtin_amdgcn_s_setprio(0);
      asm volatile("s_barrier" ::: "memory");
    }
    {
      bf16x8 a2 = *(const bf16x8*)(Abuf + rA[2]*128 + ((64 + g*16) ^ ((rA[2]&7)<<4)));
      bf16x8 a3 = *(const bf16x8*)(Abuf + rA[3]*128 + ((64 + g*16) ^ ((rA[3]&7)<<4)));
      if (st){ stageB(t+2,b2,3); }
      asm volatile("s_barrier" ::: "memory");
      __builtin_amdgcn_s_setprio(1);
      #pragma unroll
      for (int ni=0;ni<4;ni++){
        acc[2][ni] = __builtin_amdgcn_mfma_f32_16x16x32_bf16(a2, bfr[ni], acc[2][ni],0,0,0);
        acc[3][ni] = __builtin_amdgcn_mfma_f32_16x16x32_bf16(a3, bfr[ni], acc[3][ni],0,0,0);
      }
      __builtin_amdgcn_s_setprio(0);
      if (t + 1 < 32){
        if (st) asm volatile("s_waitcnt vmcnt(6)" ::: "memory");
        else    asm volatile("s_waitcnt vmcnt(0)" ::: "memory");
      }
      asm volatile("s_barrier" ::: "memory");
    }
    char* tmp = b0; b0 = b1; b1 = b2; b2 = tmp;
  }

  if constexpr (MODE == 3 || MODE == 4){
    float* lf = (float*)lds;                 // [128][260] fp32, biased values
    #pragma unroll
    for (int mi=0;mi<4;mi++){
      #pragma unroll
      for (int ni=0;ni<4;ni++){
        int fl = wn*64 + ni*16 + c16;
        float bv = bias[rowB0 + fl];
        #pragma unroll
        for (int j=0;j<4;j++){
          int ml = wm*64 + mi*16 + g*4 + j;
          lf[ml*260 + fl] = acc[mi][ni][j] + bv;
        }
      }
    }
    __syncthreads();
    #pragma unroll
    for (int mi=0;mi<4;mi++){
      #pragma unroll
      for (int ni=0;ni<4;ni++){
        int fl = wn*64 + ni*16 + c16;
        int f  = rowB0 + fl;
        float bv = bias[f];
        int i  = fl & 63;
        #pragma unroll
        for (int j=0;j<4;j++){
          int ml = wm*64 + mi*16 + g*4 + j;
          int m  = rowA0 + ml;
          int spos = m & (SS-1);
          float c  = cost[spos*64 + i];
          float sn = sint[spos*64 + i];
          float self = acc[mi][ni][j] + bv;
          float part = lf[ml*260 + (fl ^ 64)];
          float v = (fl & 64) ? (self*c + part*sn) : (self*c - part*sn);
          if constexpr (MODE == 3) v *= QSCL;
          ((__hip_bfloat16*)Cout)[(size_t)m*EE + f] = f2bf(v);
        }
      }
    }
  } else {
    #pragma unroll
    for (int mi=0;mi<4;mi++){
      #pragma unroll
      for (int ni=0;ni<4;ni++){
        int f = rowB0 + wn*64 + ni*16 + c16;
        float bv = bias[f];
        #pragma unroll
        for (int j=0;j<4;j++){
          int m = rowA0 + wm*64 + mi*16 + g*4 + j;
          float v = acc[mi][ni][j] + bv;
          if constexpr (MODE == 0) {
            ((__hip_bfloat16*)Cout)[(size_t)m*EE + f] = f2bf(v);
          } else if constexpr (MODE == 1) {
            int b = m >> 11, s = m & (SS-1);
            ((__hip_bfloat16*)Cout)[((size_t)(b*EE + f))*SS + s] = f2bf(v);
          } else {
            ((float*)Cout)[(size_t)m*EE + f] = v;
          }
        }
      }
    }
  }
}

// ---------------- flash attention (causal), swapped-QK^T 32x32x16, 4 waves x 32q ----------------
// R13/R16 structure (phase-skew, conflict-free swizzles, T13 defer, masked-tile skip)
// + counted-vmcnt barriers: per iter, 2 raw s_barriers with vmcnt(8) (K/V of this
// iter = 8-oldest loads), never a full vmem drain — next iter's staging stays in
// flight across both barriers.
__global__ __launch_bounds__(256, 2) void attn_kernel(const __hip_bfloat16* __restrict__ qg,
    const __hip_bfloat16* __restrict__ kg, const __hip_bfloat16* __restrict__ vtg,
    __hip_bfloat16* __restrict__ og){
  __shared__ short Ks[2][64*128];    // 16KB x2
  __shared__ short Vs3[3][64*128];   // 16KB x3, [64 rows][256B]
  const int tid=threadIdx.x, wid=tid>>6, lane=tid&63;
  const int c32 = lane & 31, hi = lane >> 5;
  const bool skew = (wid >= 2);
  const int id = blockIdx.x;
  const int u = id & 255;
  const int bh = u & 31, pr = u >> 5;
  const int qtile = (id < 256) ? (15 - pr) : pr;
  const int b = bh >> 4, h = bh & 15;
  const int q0 = qtile*128, qw = q0 + wid*32;
  const int qglob = qw + c32;
  const int niter = 2*qtile + 2;

  const char* kb8 = (const char*)(kg + ((size_t)b*SS)*EE + h*DD);
  const char* vb8 = (const char*)(vtg + (size_t)bh*DD*SS);

  const char* qrow = (const char*)(qg + ((size_t)(b*SS + qglob))*EE + h*DD);
  bf16x8 qf[8];
  #pragma unroll
  for (int s=0;s<8;s++) qf[s] = *(const bf16x8*)(qrow + s*32 + hi*16);

  f32x16 pacc[4] = {};
  float mrun = -INFINITY, lrun = 0.f;
  bf16x8 pf[4];

  auto stageK = [&](int kv, short* dst){
    #pragma unroll
    for (int i=0;i<4;i++){
      int base = i*4096 + wid*1024;
      int lb = base + lane*16;
      int r = lb >> 8, cb = lb & 255;
      gload16(kb8 + (size_t)(kv + r)*4096 + (cb ^ ((r&15)<<4)), (char*)dst + base);
    }
  };
  auto stageV = [&](int kv, short* dst){
    #pragma unroll
    for (int i=0;i<4;i++){
      int base = i*4096 + wid*1024;
      int lb = base + lane*16;
      int r = lb >> 8;
      int cs = (lb & 255) ^ ((r&15)<<4);
      int dsrc = r + ((cs >> 7) << 6);
      int kcol = cs & 127;
      gload16(vb8 + (size_t)dsrc*4096 + (size_t)kv*2 + kcol, (char*)dst + base);
    }
  };
  auto pvadd = [&](const short* vbuf){
    const char* Vb = (const char*)vbuf;
    __builtin_amdgcn_s_setprio(1);
    #pragma unroll
    for (int ds=0; ds<4; ds++){
      int d = ds*32 + c32;
      int rr = d & 63;
      int half = (d >> 6) << 7;
      const char* vr = Vb + rr*256;
      int vsw = (rr&15) << 4;
      #pragma unroll
      for (int ks=0; ks<4; ks++){
        bf16x8 vf = *(const bf16x8*)(vr + ((half + ks*32 + hi*16) ^ vsw));
        pacc[ds] = __builtin_amdgcn_mfma_f32_32x32x16_bf16(vf, pf[ks], pacc[ds], 0,0,0);
      }
    }
    __builtin_amdgcn_s_setprio(0);
  };

  short* va = Vs3[0]; short* vbuf = Vs3[1]; short* vc = Vs3[2];
  short* kc = Ks[0];  short* kn = Ks[1];

  stageK(0, kc); stageV(0, vbuf);
  asm volatile("s_waitcnt vmcnt(0)" ::: "memory");
  asm volatile("s_barrier" ::: "memory");

  #pragma unroll 1
  for (int it = 0; it < niter; ++it){
    const int kv0 = it*64;
    const bool pre = (it + 1 < niter);
    if (pre){ stageK(kv0+64, kn); stageV(kv0+64, vc); }   // 8 loads, stay in flight

    // skewed waves: deferred PV(it-1) from va (two-generations-old buffer, safe)
    if (skew && it > 0) pvadd(va);

    // own K(it),V(it) are the 8-oldest outstanding loads
    if (pre) asm volatile("s_waitcnt vmcnt(8)" ::: "memory");
    else     asm volatile("s_waitcnt vmcnt(0)" ::: "memory");
    asm volatile("s_barrier" ::: "memory");   // all waves' K(it),V(it) visible

    const bool fullmask = (kv0 > qw + 31);
    if (!fullmask){
      f32x16 st0 = {}, st1 = {};
      {
        const char* Kb = (const char*)kc;
        __builtin_amdgcn_s_setprio(1);
        const int sw0 = (c32&15) << 4;
        #pragma unroll
        for (int s=0;s<8;s++){
          bf16x8 kf0 = *(const bf16x8*)(Kb + c32*256      + ((s*32 + hi*16) ^ sw0));
          bf16x8 kf1 = *(const bf16x8*)(Kb + (32+c32)*256 + ((s*32 + hi*16) ^ sw0));
          st0 = __builtin_amdgcn_mfma_f32_32x32x16_bf16(kf0, qf[s], st0, 0,0,0);
          st1 = __builtin_amdgcn_mfma_f32_32x32x16_bf16(kf1, qf[s], st1, 0,0,0);
        }
        __builtin_amdgcn_s_setprio(0);
      }

      float p[32];
      float vmax = -INFINITY;
      const bool domask = (kv0 + 63 > qw);
      #pragma unroll
      for (int r=0;r<16;r++){
        float v0 = st0[r], v1 = st1[r];
        if (domask){
          int kvo = (r&3) + 8*(r>>2) + 4*hi;
          if (kv0 + kvo > qglob)      v0 = -INFINITY;
          if (kv0 + 32 + kvo > qglob) v1 = -INFINITY;
        }
        p[r] = v0; p[16+r] = v1;
        vmax = fmaxf(vmax, fmaxf(v0, v1));
      }
      vmax = fmaxf(vmax, __shfl_xor(vmax, 32));

      const bool rescale = !__all(vmax <= mrun + 8.0f);
      float mnew = mrun;
      if (rescale){
        mnew = fmaxf(mrun, vmax);
        const float rs = exp2f(mrun - mnew);
        mrun = mnew;
        lrun *= rs;
        #pragma unroll
        for (int ds=0; ds<4; ds++)
          #pragma unroll
          for (int r=0;r<16;r++) pacc[ds][r] *= rs;
      }

      float s0=0.f, s1=0.f, s2=0.f, s3=0.f;
      #pragma unroll
      for (int i=0;i<8;i++){
        p[i]    = exp2f(p[i]    - mnew); s0 += p[i];
        p[8+i]  = exp2f(p[8+i]  - mnew); s1 += p[8+i];
        p[16+i] = exp2f(p[16+i] - mnew); s2 += p[16+i];
        p[24+i] = exp2f(p[24+i] - mnew); s3 += p[24+i];
      }
      float ps = (s0 + s1) + (s2 + s3);
      ps += __shfl_xor(ps, 32);
      lrun += ps;

      unsigned w[2][4][2];
      #pragma unroll
      for (int T=0;T<2;T++)
        #pragma unroll
        for (int m=0;m<4;m++)
          #pragma unroll
          for (int uu=0;uu<2;uu++)
            w[T][m][uu] = pk2(p[T*16 + 4*m + 2*uu], p[T*16 + 4*m + 2*uu + 1]);

      #pragma unroll
      for (int ks=0; ks<4; ks++){
        int T = ks>>1, lo2 = (ks&1)*2;
        unsigned o0 = hi ? w[T][lo2+1][0] : w[T][lo2+0][0];
        unsigned o1 = hi ? w[T][lo2+1][1] : w[T][lo2+0][1];
        unsigned x0 = hi ? w[T][lo2+0][0] : w[T][lo2+1][0];
        unsigned x1 = hi ? w[T][lo2+0][1] : w[T][lo2+1][1];
        unsigned r0 = (unsigned)__shfl_xor((int)x0, 32);
        unsigned r1 = (unsigned)__shfl_xor((int)x1, 32);
        union { u32x4 u4; bf16x8 h8; } cvt;
        cvt.u4[0] = hi ? r0 : o0;
        cvt.u4[1] = hi ? r1 : o1;
        cvt.u4[2] = hi ? o0 : r0;
        cvt.u4[3] = hi ? o1 : r1;
        pf[ks] = cvt.h8;
      }

      if (!skew) pvadd(vbuf);
    }

    asm volatile("s_barrier" ::: "memory");   // seal reads of kc/va/vbuf before restaging
    short* t = va; va = vbuf; vbuf = vc; vc = t;
    short* tk = kc; kc = kn; kn = tk;
  }

  if (skew) pvadd(va);

  const float invl = 1.0f / lrun;
  char* orow = (char*)(og + ((size_t)(b*SS + qglob))*EE + h*DD);
  #pragma unroll
  for (int ds=0; ds<4; ds++){
    #pragma unroll
    for (int m=0;m<4;m++){
      int d0 = ds*32 + 8*m + 4*hi;
      short4 s4;
      s4.x = f2bs(pacc[ds][4*m+0]*invl);
      s4.y = f2bs(pacc[ds][4*m+1]*invl);
      s4.z = f2bs(pacc[ds][4*m+2]*invl);
      s4.w = f2bs(pacc[ds][4*m+3]*invl);
      *(short4*)(orow + d0*2) = s4;
    }
  }
}

extern "C" void kernel_launch(void* const* d_in, const int* in_sizes, int n_in,
                              void* d_out, int out_size, void* d_ws, size_t ws_size,
                              hipStream_t stream){
  const float* x  = (const float*)d_in[0];
  const float* Wq = (const float*)d_in[1];
  const float* bq = (const float*)d_in[2];
  const float* Wk = (const float*)d_in[3];
  const float* bk = (const float*)d_in[4];
  const float* Wv = (const float*)d_in[5];
  const float* bv = (const float*)d_in[6];
  const float* Wp = (const float*)d_in[7];
  const float* bp = (const float*)d_in[8];
  float* out = (float*)d_out;

  char* ws = (char*)d_ws;
  size_t off = 0;
  auto alloc = [&](size_t bytes){ void* p = ws + off; off += (bytes + 255) & ~(size_t)255; return p; };
  const size_t nx = (size_t)MM*EE;
  const size_t nw = (size_t)EE*EE;
  __hip_bfloat16* xb  = (__hip_bfloat16*)alloc(nx*2);
  __hip_bfloat16* wqb = (__hip_bfloat16*)alloc(nw*2);
  __hip_bfloat16* wkb = (__hip_bfloat16*)alloc(nw*2);
  __hip_bfloat16* wvb = (__hip_bfloat16*)alloc(nw*2);
  __hip_bfloat16* wpb = (__hip_bfloat16*)alloc(nw*2);
  __hip_bfloat16* qb  = (__hip_bfloat16*)alloc(nx*2);
  __hip_bfloat16* kb  = (__hip_bfloat16*)alloc(nx*2);
  __hip_bfloat16* vtb = (__hip_bfloat16*)alloc(nx*2);
  __hip_bfloat16* ob  = (__hip_bfloat16*)alloc(nx*2);
  float* cost = (float*)alloc((size_t)SS*64*4);
  float* sint = (float*)alloc((size_t)SS*64*4);

  P5 p5{x, Wq, Wk, Wv, Wp, xb, wqb, wkb, wvb, wpb, (int)(nx/4), (int)(nw/4)};
  cvt5_kernel<<<dim3((int)(nx/4/256), 5), 256, 0, stream>>>(p5);
  rope_tables_kernel<<<SS*64/256, 256, 0, stream>>>(cost, sint);

  gemm256<3><<<256, 512, 0, stream>>>(xb, wqb, bq, qb,  cost, sint);   // q + RoPE + QSCL
  gemm256<4><<<256, 512, 0, stream>>>(xb, wkb, bk, kb,  cost, sint);   // k + RoPE
  gemm256<1><<<256, 512, 0, stream>>>(xb, wvb, bv, vtb, nullptr, nullptr);

  attn_kernel<<<dim3(512), 256, 0, stream>>>(qb, kb, vtb, ob);

  gemm256<2><<<256, 512, 0, stream>>>(ob, wpb, bp, out, nullptr, nullptr);
}

// Round 19
// 263.682 us; speedup vs baseline: 1.0473x; 1.0473x over previous
//
#include <hip/hip_runtime.h>
#include <hip/hip_bf16.h>
#include <math.h>

#define BB 2
#define SS 2048
#define EE 2048
#define HH 16
#define DD 128
#define MM (BB*SS)

typedef __attribute__((ext_vector_type(8))) short bf16x8;
typedef __attribute__((ext_vector_type(4))) float f32x4;
typedef __attribute__((ext_vector_type(16))) float f32x16;
typedef __attribute__((ext_vector_type(4))) unsigned u32x4;

__device__ inline float bf2f(const __hip_bfloat16 h){ return __bfloat162float(h); }
__device__ inline __hip_bfloat16 f2bf(float f){ return __float2bfloat16(f); }
__device__ inline short f2bs(float f){
  union { __hip_bfloat16 h; short s; } u; u.h = __float2bfloat16(f); return u.s;
}
__device__ inline unsigned pk2(float a, float b){
  union { __hip_bfloat162 h2; unsigned u; } x;
  x.h2 = __float22bfloat162_rn(float2{a,b}); return x.u;   // low half = a
}

__device__ inline void gload16(const void* g, void* l){
  __builtin_amdgcn_global_load_lds((const __attribute__((address_space(1))) void*)g,
      (__attribute__((address_space(3))) void*)l, 16, 0, 0);
}

// 1/sqrt(128) * log2(e): folded into Q during its GEMM-epilogue RoPE
#define QSCL 0.12754614533018515f

// ---------------- fp32 -> bf16 convert, 5 tensors in one launch ----------------
struct P5 { const float* s0; const float* s1; const float* s2; const float* s3; const float* s4;
            __hip_bfloat16* d0; __hip_bfloat16* d1; __hip_bfloat16* d2; __hip_bfloat16* d3; __hip_bfloat16* d4;
            int n0; int n1; };
__global__ void cvt5_kernel(P5 p){
  int w = blockIdx.y;
  const float* in = w==0 ? p.s0 : w==1 ? p.s1 : w==2 ? p.s2 : w==3 ? p.s3 : p.s4;
  __hip_bfloat16* out = w==0 ? p.d0 : w==1 ? p.d1 : w==2 ? p.d2 : w==3 ? p.d3 : p.d4;
  int n4 = w==0 ? p.n0 : p.n1;
  int i = blockIdx.x*256 + threadIdx.x;
  if (i >= n4) return;
  float4 v = ((const float4*)in)[i];
  union { short4 s4; short s[4]; } u;
  u.s[0] = f2bs(v.x); u.s[1] = f2bs(v.y); u.s[2] = f2bs(v.z); u.s[3] = f2bs(v.w);
  ((short4*)out)[i] = u.s4;
}

// ---------------- RoPE tables ----------------
__global__ void rope_tables_kernel(float* __restrict__ cost, float* __restrict__ sint){
  int idx = blockIdx.x*256 + threadIdx.x;  // SS*64
  int s = idx >> 6, i = idx & 63;
  double inv = exp(-log(10000.0) * (double)i / 64.0);
  double f = (double)s * inv;
  cost[idx] = (float)cos(f);
  sint[idx] = (float)sin(f);
}

// ---------------- bf16 GEMM, 128x256 tile, BK=64, 8 waves, 4-phase pipeline ----------------
// MODE 0: bf16 C[m*EE+f]; MODE 1: bf16 vt[(b*EE+f)*SS+s]; MODE 2: fp32 C;
// MODE 3: bf16 C with fused RoPE + QSCL (q); MODE 4: bf16 C with fused RoPE (k).
template<int MODE>
__global__ __launch_bounds__(512) void gemm256(const __hip_bfloat16* __restrict__ A,
        const __hip_bfloat16* __restrict__ Bw, const float* __restrict__ bias,
        void* __restrict__ Cout,
        const float* __restrict__ cost, const float* __restrict__ sint){
  __shared__ __align__(1024) char lds[147456];   // 3 x (A 16KB + B 32KB); reused by rope epilogue
  const int tid = threadIdx.x, wid = tid>>6, lane = tid&63, g = lane>>4, c16 = lane&15;
  const int wm = wid>>2, wn = wid&3;
  const int orig = blockIdx.x;
  const int wg = (orig & 7)*32 + (orig >> 3);   // bijective XCD swizzle (grid 256)
  const int bm = wg & 31, bn = wg >> 5;
  const int rowA0 = bm*128, rowB0 = bn*256;
  const char* Ab8 = (const char*)A + (size_t)rowA0*4096;
  const char* Bb8 = (const char*)Bw + (size_t)rowB0*4096;

  f32x4 acc[4][4] = {};

  auto stageA = [&](int t, char* buf, int i){
    int off = i*8192 + tid*16;
    int r = off >> 7;
    int cs = (off & 127) ^ ((r&7)<<4);
    gload16(Ab8 + (size_t)r*4096 + t*128 + cs, buf + i*8192 + wid*1024);
  };
  auto stageB = [&](int t, char* buf, int i){
    int off = i*8192 + tid*16;
    int r = off >> 7;
    int cs = (off & 127) ^ ((r&7)<<4);
    gload16(Bb8 + (size_t)r*4096 + t*128 + cs, buf + 16384 + i*8192 + wid*1024);
  };

  char* b0 = lds;            // tile t   (read)
  char* b1 = lds + 49152;    // tile t+1 (landed/in flight)
  char* b2 = lds + 98304;    // tile t+2 (stage target)

  stageA(0,b0,0); stageA(0,b0,1);
  stageB(0,b0,0); stageB(0,b0,1); stageB(0,b0,2); stageB(0,b0,3);
  stageA(1,b1,0); stageA(1,b1,1);
  stageB(1,b1,0); stageB(1,b1,1); stageB(1,b1,2); stageB(1,b1,3);
  asm volatile("s_waitcnt vmcnt(6)" ::: "memory");
  asm volatile("s_barrier" ::: "memory");

  const int rB[4] = { wn*64 + 0*16 + c16, wn*64 + 1*16 + c16, wn*64 + 2*16 + c16, wn*64 + 3*16 + c16 };
  const int rA[4] = { wm*64 + 0*16 + c16, wm*64 + 1*16 + c16, wm*64 + 2*16 + c16, wm*64 + 3*16 + c16 };

  #pragma unroll 1
  for (int t = 0; t < 32; ++t){
    const char* Abuf = b0;
    const char* Bbuf = b0 + 16384;
    const bool st = (t + 2 < 32);
    bf16x8 bfr[4];

    // ---- ph0: kk=0, mi 0-1 ----
    {
      #pragma unroll
      for (int ni=0;ni<4;ni++)
        bfr[ni] = *(const bf16x8*)(Bbuf + rB[ni]*128 + ((g*16) ^ ((rB[ni]&7)<<4)));
      bf16x8 a0 = *(const bf16x8*)(Abuf + rA[0]*128 + ((g*16) ^ ((rA[0]&7)<<4)));
      bf16x8 a1 = *(const bf16x8*)(Abuf + rA[1]*128 + ((g*16) ^ ((rA[1]&7)<<4)));
      if (st){ stageA(t+2,b2,0); stageA(t+2,b2,1); }
      asm volatile("s_barrier" ::: "memory");
      __builtin_amdgcn_s_setprio(1);
      #pragma unroll
      for (int ni=0;ni<4;ni++){
        acc[0][ni] = __builtin_amdgcn_mfma_f32_16x16x32_bf16(a0, bfr[ni], acc[0][ni],0,0,0);
        acc[1][ni] = __builtin_amdgcn_mfma_f32_16x16x32_bf16(a1, bfr[ni], acc[1][ni],0,0,0);
      }
      __builtin_amdgcn_s_setprio(0);
      asm volatile("s_barrier" ::: "memory");
    }
    // ---- ph1: kk=0, mi 2-3 ----
    {
      bf16x8 a2 = *(const bf16x8*)(Abuf + rA[2]*128 + ((g*16) ^ ((rA[2]&7)<<4)));
      bf16x8 a3 = *(const bf16x8*)(Abuf + rA[3]*128 + ((g*16) ^ ((rA[3]&7)<<4)));
      if (st){ stageB(t+2,b2,0); stageB(t+2,b2,1); }
      asm volatile("s_barrier" ::: "memory");
      __builtin_amdgcn_s_setprio(1);
      #pragma unroll
      for (int ni=0;ni<4;ni++){
        acc[2][ni] = __builtin_amdgcn_mfma_f32_16x16x32_bf16(a2, bfr[ni], acc[2][ni],0,0,0);
        acc[3][ni] = __builtin_amdgcn_mfma_f32_16x16x32_bf16(a3, bfr[ni], acc[3][ni],0,0,0);
      }
      __builtin_amdgcn_s_setprio(0);
      asm volatile("s_barrier" ::: "memory");
    }
    // ---- ph2: kk=1, mi 0-1 ----
    {
      #pragma unroll
      for (int ni=0;ni<4;ni++)
        bfr[ni] = *(const bf16x8*)(Bbuf + rB[ni]*128 + ((64 + g*16) ^ ((rB[ni]&7)<<4)));
      bf16x8 a0 = *(const bf16x8*)(Abuf + rA[0]*128 + ((64 + g*16) ^ ((rA[0]&7)<<4)));
      bf16x8 a1 = *(const bf16x8*)(Abuf + rA[1]*128 + ((64 + g*16) ^ ((rA[1]&7)<<4)));
      if (st){ stageB(t+2,b2,2); }
      asm volatile("s_barrier" ::: "memory");
      __builtin_amdgcn_s_setprio(1);
      #pragma unroll
      for (int ni=0;ni<4;ni++){
        acc[0][ni] = __builtin_amdgcn_mfma_f32_16x16x32_bf16(a0, bfr[ni], acc[0][ni],0,0,0);
        acc[1][ni] = __builtin_amdgcn_mfma_f32_16x16x32_bf16(a1, bfr[ni], acc[1][ni],0,0,0);
      }
      __builtin_amdgcn_s_setprio(0);
      asm volatile("s_barrier" ::: "memory");
    }
    // ---- ph3: kk=1, mi 2-3; tile-boundary vmcnt ----
    {
      bf16x8 a2 = *(const bf16x8*)(Abuf + rA[2]*128 + ((64 + g*16) ^ ((rA[2]&7)<<4)));
      bf16x8 a3 = *(const bf16x8*)(Abuf + rA[3]*128 + ((64 + g*16) ^ ((rA[3]&7)<<4)));
      if (st){ stageB(t+2,b2,3); }
      asm volatile("s_barrier" ::: "memory");
      __builtin_amdgcn_s_setprio(1);
      #pragma unroll
      for (int ni=0;ni<4;ni++){
        acc[2][ni] = __builtin_amdgcn_mfma_f32_16x16x32_bf16(a2, bfr[ni], acc[2][ni],0,0,0);
        acc[3][ni] = __builtin_amdgcn_mfma_f32_16x16x32_bf16(a3, bfr[ni], acc[3][ni],0,0,0);
      }
      __builtin_amdgcn_s_setprio(0);
      if (t + 1 < 32){
        if (st) asm volatile("s_waitcnt vmcnt(6)" ::: "memory");
        else    asm volatile("s_waitcnt vmcnt(0)" ::: "memory");
      }
      asm volatile("s_barrier" ::: "memory");
    }
    char* tmp = b0; b0 = b1; b1 = b2; b2 = tmp;
  }

  if constexpr (MODE == 3 || MODE == 4){
    // ---- fused RoPE epilogue: partner column f^64 exchanged via LDS ----
    float* lf = (float*)lds;                 // [128][260] fp32, biased values
    #pragma unroll
    for (int mi=0;mi<4;mi++){
      #pragma unroll
      for (int ni=0;ni<4;ni++){
        int fl = wn*64 + ni*16 + c16;
        float bv = bias[rowB0 + fl];
        #pragma unroll
        for (int j=0;j<4;j++){
          int ml = wm*64 + mi*16 + g*4 + j;
          lf[ml*260 + fl] = acc[mi][ni][j] + bv;
        }
      }
    }
    __syncthreads();
    #pragma unroll
    for (int mi=0;mi<4;mi++){
      #pragma unroll
      for (int ni=0;ni<4;ni++){
        int fl = wn*64 + ni*16 + c16;
        int f  = rowB0 + fl;
        float bv = bias[f];
        int i  = fl & 63;
        #pragma unroll
        for (int j=0;j<4;j++){
          int ml = wm*64 + mi*16 + g*4 + j;
          int m  = rowA0 + ml;
          int spos = m & (SS-1);
          float c  = cost[spos*64 + i];
          float sn = sint[spos*64 + i];
          float self = acc[mi][ni][j] + bv;
          float part = lf[ml*260 + (fl ^ 64)];
          float v = (fl & 64) ? (self*c + part*sn) : (self*c - part*sn);
          if constexpr (MODE == 3) v *= QSCL;
          ((__hip_bfloat16*)Cout)[(size_t)m*EE + f] = f2bf(v);
        }
      }
    }
  } else {
    #pragma unroll
    for (int mi=0;mi<4;mi++){
      #pragma unroll
      for (int ni=0;ni<4;ni++){
        int f = rowB0 + wn*64 + ni*16 + c16;
        float bv = bias[f];
        #pragma unroll
        for (int j=0;j<4;j++){
          int m = rowA0 + wm*64 + mi*16 + g*4 + j;
          float v = acc[mi][ni][j] + bv;
          if constexpr (MODE == 0) {
            ((__hip_bfloat16*)Cout)[(size_t)m*EE + f] = f2bf(v);
          } else if constexpr (MODE == 1) {
            int b = m >> 11, s = m & (SS-1);
            ((__hip_bfloat16*)Cout)[((size_t)(b*EE + f))*SS + s] = f2bf(v);
          } else {
            ((float*)Cout)[(size_t)m*EE + f] = v;
          }
        }
      }
    }
  }
}

// ---------------- flash attention (causal), swapped-QK^T 32x32x16, 4 waves x 32q ----------------
// R13/R16 structure: phase-skew, conflict-free swizzles, T13 defer, masked-tile skip.
__global__ __launch_bounds__(256, 2) void attn_kernel(const __hip_bfloat16* __restrict__ qg,
    const __hip_bfloat16* __restrict__ kg, const __hip_bfloat16* __restrict__ vtg,
    __hip_bfloat16* __restrict__ og){
  __shared__ short Ks[2][64*128];    // 16KB x2
  __shared__ short Vs3[3][64*128];   // 16KB x3, [64 rows][256B]
  const int tid=threadIdx.x, wid=tid>>6, lane=tid&63;
  const int c32 = lane & 31, hi = lane >> 5;
  const bool skew = (wid >= 2);
  const int id = blockIdx.x;
  const int u = id & 255;
  const int bh = u & 31, pr = u >> 5;
  const int qtile = (id < 256) ? (15 - pr) : pr;
  const int b = bh >> 4, h = bh & 15;
  const int q0 = qtile*128, qw = q0 + wid*32;
  const int qglob = qw + c32;
  const int niter = 2*qtile + 2;

  const char* kb8 = (const char*)(kg + ((size_t)b*SS)*EE + h*DD);
  const char* vb8 = (const char*)(vtg + (size_t)bh*DD*SS);

  const char* qrow = (const char*)(qg + ((size_t)(b*SS + qglob))*EE + h*DD);
  bf16x8 qf[8];
  #pragma unroll
  for (int s=0;s<8;s++) qf[s] = *(const bf16x8*)(qrow + s*32 + hi*16);

  f32x16 pacc[4] = {};
  float mrun = -INFINITY, lrun = 0.f;
  bf16x8 pf[4];

  auto stageK = [&](int kv, short* dst){
    #pragma unroll
    for (int i=0;i<4;i++){
      int base = i*4096 + wid*1024;
      int lb = base + lane*16;
      int r = lb >> 8, cb = lb & 255;
      gload16(kb8 + (size_t)(kv + r)*4096 + (cb ^ ((r&15)<<4)), (char*)dst + base);
    }
  };
  auto stageV = [&](int kv, short* dst){
    #pragma unroll
    for (int i=0;i<4;i++){
      int base = i*4096 + wid*1024;
      int lb = base + lane*16;
      int r = lb >> 8;
      int cs = (lb & 255) ^ ((r&15)<<4);
      int dsrc = r + ((cs >> 7) << 6);
      int kcol = cs & 127;
      gload16(vb8 + (size_t)dsrc*4096 + (size_t)kv*2 + kcol, (char*)dst + base);
    }
  };
  auto pvadd = [&](const short* vbuf){
    const char* Vb = (const char*)vbuf;
    __builtin_amdgcn_s_setprio(1);
    #pragma unroll
    for (int ds=0; ds<4; ds++){
      int d = ds*32 + c32;
      int rr = d & 63;
      int half = (d >> 6) << 7;
      const char* vr = Vb + rr*256;
      int vsw = (rr&15) << 4;
      #pragma unroll
      for (int ks=0; ks<4; ks++){
        bf16x8 vf = *(const bf16x8*)(vr + ((half + ks*32 + hi*16) ^ vsw));
        pacc[ds] = __builtin_amdgcn_mfma_f32_32x32x16_bf16(vf, pf[ks], pacc[ds], 0,0,0);
      }
    }
    __builtin_amdgcn_s_setprio(0);
  };

  short* va = Vs3[0]; short* vbuf = Vs3[1]; short* vc = Vs3[2];
  short* kc = Ks[0];  short* kn = Ks[1];

  stageK(0, kc); stageV(0, vbuf);
  __syncthreads();

  #pragma unroll 1
  for (int it = 0; it < niter; ++it){
    const int kv0 = it*64;
    if (it + 1 < niter){ stageK(kv0+64, kn); stageV(kv0+64, vc); }

    if (skew && it > 0) pvadd(va);

    const bool fullmask = (kv0 > qw + 31);
    if (!fullmask){
      f32x16 st0 = {}, st1 = {};
      {
        const char* Kb = (const char*)kc;
        __builtin_amdgcn_s_setprio(1);
        const int sw0 = (c32&15) << 4;
        #pragma unroll
        for (int s=0;s<8;s++){
          bf16x8 kf0 = *(const bf16x8*)(Kb + c32*256      + ((s*32 + hi*16) ^ sw0));
          bf16x8 kf1 = *(const bf16x8*)(Kb + (32+c32)*256 + ((s*32 + hi*16) ^ sw0));
          st0 = __builtin_amdgcn_mfma_f32_32x32x16_bf16(kf0, qf[s], st0, 0,0,0);
          st1 = __builtin_amdgcn_mfma_f32_32x32x16_bf16(kf1, qf[s], st1, 0,0,0);
        }
        __builtin_amdgcn_s_setprio(0);
      }

      float p[32];
      float vmax = -INFINITY;
      const bool domask = (kv0 + 63 > qw);
      #pragma unroll
      for (int r=0;r<16;r++){
        float v0 = st0[r], v1 = st1[r];
        if (domask){
          int kvo = (r&3) + 8*(r>>2) + 4*hi;
          if (kv0 + kvo > qglob)      v0 = -INFINITY;
          if (kv0 + 32 + kvo > qglob) v1 = -INFINITY;
        }
        p[r] = v0; p[16+r] = v1;
        vmax = fmaxf(vmax, fmaxf(v0, v1));
      }
      vmax = fmaxf(vmax, __shfl_xor(vmax, 32));

      const bool rescale = !__all(vmax <= mrun + 8.0f);
      float mnew = mrun;
      if (rescale){
        mnew = fmaxf(mrun, vmax);
        const float rs = exp2f(mrun - mnew);
        mrun = mnew;
        lrun *= rs;
        #pragma unroll
        for (int ds=0; ds<4; ds++)
          #pragma unroll
          for (int r=0;r<16;r++) pacc[ds][r] *= rs;
      }

      float s0=0.f, s1=0.f, s2=0.f, s3=0.f;
      #pragma unroll
      for (int i=0;i<8;i++){
        p[i]    = exp2f(p[i]    - mnew); s0 += p[i];
        p[8+i]  = exp2f(p[8+i]  - mnew); s1 += p[8+i];
        p[16+i] = exp2f(p[16+i] - mnew); s2 += p[16+i];
        p[24+i] = exp2f(p[24+i] - mnew); s3 += p[24+i];
      }
      float ps = (s0 + s1) + (s2 + s3);
      ps += __shfl_xor(ps, 32);
      lrun += ps;

      unsigned w[2][4][2];
      #pragma unroll
      for (int T=0;T<2;T++)
        #pragma unroll
        for (int m=0;m<4;m++)
          #pragma unroll
          for (int uu=0;uu<2;uu++)
            w[T][m][uu] = pk2(p[T*16 + 4*m + 2*uu], p[T*16 + 4*m + 2*uu + 1]);

      #pragma unroll
      for (int ks=0; ks<4; ks++){
        int T = ks>>1, lo2 = (ks&1)*2;
        unsigned o0 = hi ? w[T][lo2+1][0] : w[T][lo2+0][0];
        unsigned o1 = hi ? w[T][lo2+1][1] : w[T][lo2+0][1];
        unsigned x0 = hi ? w[T][lo2+0][0] : w[T][lo2+1][0];
        unsigned x1 = hi ? w[T][lo2+0][1] : w[T][lo2+1][1];
        unsigned r0 = (unsigned)__shfl_xor((int)x0, 32);
        unsigned r1 = (unsigned)__shfl_xor((int)x1, 32);
        union { u32x4 u4; bf16x8 h8; } cvt;
        cvt.u4[0] = hi ? r0 : o0;
        cvt.u4[1] = hi ? r1 : o1;
        cvt.u4[2] = hi ? o0 : r0;
        cvt.u4[3] = hi ? o1 : r1;
        pf[ks] = cvt.h8;
      }

      if (!skew) pvadd(vbuf);
    }

    __syncthreads();
    short* t = va; va = vbuf; vbuf = vc; vc = t;
    short* tk = kc; kc = kn; kn = tk;
  }

  if (skew) pvadd(va);

  const float invl = 1.0f / lrun;
  char* orow = (char*)(og + ((size_t)(b*SS + qglob))*EE + h*DD);
  #pragma unroll
  for (int ds=0; ds<4; ds++){
    #pragma unroll
    for (int m=0;m<4;m++){
      int d0 = ds*32 + 8*m + 4*hi;
      short4 s4;
      s4.x = f2bs(pacc[ds][4*m+0]*invl);
      s4.y = f2bs(pacc[ds][4*m+1]*invl);
      s4.z = f2bs(pacc[ds][4*m+2]*invl);
      s4.w = f2bs(pacc[ds][4*m+3]*invl);
      *(short4*)(orow + d0*2) = s4;
    }
  }
}

extern "C" void kernel_launch(void* const* d_in, const int* in_sizes, int n_in,
                              void* d_out, int out_size, void* d_ws, size_t ws_size,
                              hipStream_t stream){
  const float* x  = (const float*)d_in[0];
  const float* Wq = (const float*)d_in[1];
  const float* bq = (const float*)d_in[2];
  const float* Wk = (const float*)d_in[3];
  const float* bk = (const float*)d_in[4];
  const float* Wv = (const float*)d_in[5];
  const float* bv = (const float*)d_in[6];
  const float* Wp = (const float*)d_in[7];
  const float* bp = (const float*)d_in[8];
  float* out = (float*)d_out;

  char* ws = (char*)d_ws;
  size_t off = 0;
  auto alloc = [&](size_t bytes){ void* p = ws + off; off += (bytes + 255) & ~(size_t)255; return p; };
  const size_t nx = (size_t)MM*EE;
  const size_t nw = (size_t)EE*EE;
  __hip_bfloat16* xb  = (__hip_bfloat16*)alloc(nx*2);
  __hip_bfloat16* wqb = (__hip_bfloat16*)alloc(nw*2);
  __hip_bfloat16* wkb = (__hip_bfloat16*)alloc(nw*2);
  __hip_bfloat16* wvb = (__hip_bfloat16*)alloc(nw*2);
  __hip_bfloat16* wpb = (__hip_bfloat16*)alloc(nw*2);
  __hip_bfloat16* qb  = (__hip_bfloat16*)alloc(nx*2);
  __hip_bfloat16* kb  = (__hip_bfloat16*)alloc(nx*2);
  __hip_bfloat16* vtb = (__hip_bfloat16*)alloc(nx*2);
  __hip_bfloat16* ob  = (__hip_bfloat16*)alloc(nx*2);
  float* cost = (float*)alloc((size_t)SS*64*4);
  float* sint = (float*)alloc((size_t)SS*64*4);

  P5 p5{x, Wq, Wk, Wv, Wp, xb, wqb, wkb, wvb, wpb, (int)(nx/4), (int)(nw/4)};
  cvt5_kernel<<<dim3((int)(nx/4/256), 5), 256, 0, stream>>>(p5);
  rope_tables_kernel<<<SS*64/256, 256, 0, stream>>>(cost, sint);

  gemm256<3><<<256, 512, 0, stream>>>(xb, wqb, bq, qb,  cost, sint);   // q + RoPE + QSCL
  gemm256<4><<<256, 512, 0, stream>>>(xb, wkb, bk, kb,  cost, sint);   // k + RoPE
  gemm256<1><<<256, 512, 0, stream>>>(xb, wvb, bv, vtb, nullptr, nullptr);

  attn_kernel<<<dim3(512), 256, 0, stream>>>(qb, kb, vtb, ob);

  gemm256<2><<<256, 512, 0, stream>>>(ob, wpb, bp, out, nullptr, nullptr);
}

// Round 20
// 259.246 us; speedup vs baseline: 1.0652x; 1.0171x over previous
//
#include <hip/hip_runtime.h>
#include <hip/hip_bf16.h>
#include <math.h>

#define BB 2
#define SS 2048
#define EE 2048
#define HH 16
#define DD 128
#define MM (BB*SS)

typedef __attribute__((ext_vector_type(8))) short bf16x8;
typedef __attribute__((ext_vector_type(4))) float f32x4;
typedef __attribute__((ext_vector_type(16))) float f32x16;
typedef __attribute__((ext_vector_type(4))) unsigned u32x4;

__device__ inline float bf2f(const __hip_bfloat16 h){ return __bfloat162float(h); }
__device__ inline __hip_bfloat16 f2bf(float f){ return __float2bfloat16(f); }
__device__ inline short f2bs(float f){
  union { __hip_bfloat16 h; short s; } u; u.h = __float2bfloat16(f); return u.s;
}
__device__ inline unsigned pk2(float a, float b){
  union { __hip_bfloat162 h2; unsigned u; } x;
  x.h2 = __float22bfloat162_rn(float2{a,b}); return x.u;   // low half = a
}

__device__ inline void gload16(const void* g, void* l){
  __builtin_amdgcn_global_load_lds((const __attribute__((address_space(1))) void*)g,
      (__attribute__((address_space(3))) void*)l, 16, 0, 0);
}

// 1/sqrt(128) * log2(e): folded into Q during its GEMM-epilogue RoPE
#define QSCL 0.12754614533018515f

// ---------------- prep: fp32->bf16 convert (x + 4 weights) AND rope tables, one launch ----------------
// grid (4096, 6): w=0 -> x (2 float4/thread), w=1..4 -> weights (1 float4/thread),
// w=5 -> rope tables (only first 512 blocks active).
struct P6 { const float* s0; const float* s1; const float* s2; const float* s3; const float* s4;
            __hip_bfloat16* d0; __hip_bfloat16* d1; __hip_bfloat16* d2; __hip_bfloat16* d3; __hip_bfloat16* d4;
            float* cost; float* sint; };
__global__ void prep_kernel(P6 p){
  int w = blockIdx.y;
  int bid = blockIdx.x, t = threadIdx.x;
  if (w == 5){
    int idx = bid*256 + t;           // SS*64 = 131072 = 512 blocks
    if (bid >= 512) return;
    int s = idx >> 6, i = idx & 63;
    double inv = exp(-log(10000.0) * (double)i / 64.0);
    double f = (double)s * inv;
    p.cost[idx] = (float)cos(f);
    p.sint[idx] = (float)sin(f);
    return;
  }
  if (w == 0){
    const float4* in = (const float4*)p.s0;
    short4* out = (short4*)p.d0;
    #pragma unroll
    for (int rep=0; rep<2; rep++){
      int i = (bid*2 + rep)*256 + t;     // covers 2M float4
      float4 v = in[i];
      union { short4 s4; short s[4]; } u;
      u.s[0]=f2bs(v.x); u.s[1]=f2bs(v.y); u.s[2]=f2bs(v.z); u.s[3]=f2bs(v.w);
      out[i] = u.s4;
    }
    return;
  }
  const float* in = w==1 ? p.s1 : w==2 ? p.s2 : w==3 ? p.s3 : p.s4;
  __hip_bfloat16* out = w==1 ? p.d1 : w==2 ? p.d2 : w==3 ? p.d3 : p.d4;
  int i = bid*256 + t;                   // covers 1M float4
  float4 v = ((const float4*)in)[i];
  union { short4 s4; short s[4]; } u;
  u.s[0]=f2bs(v.x); u.s[1]=f2bs(v.y); u.s[2]=f2bs(v.z); u.s[3]=f2bs(v.w);
  ((short4*)out)[i] = u.s4;
}

// ---------------- bf16 GEMM, 128x256 tile, BK=64, 8 waves, 4-phase pipeline ----------------
// MODE 0: bf16 C[m*EE+f]; MODE 1: bf16 vt[(b*EE+f)*SS+s]; MODE 2: fp32 C;
// MODE 3: bf16 C with fused RoPE + QSCL (q); MODE 4: bf16 C with fused RoPE (k).
template<int MODE>
__global__ __launch_bounds__(512) void gemm256(const __hip_bfloat16* __restrict__ A,
        const __hip_bfloat16* __restrict__ Bw, const float* __restrict__ bias,
        void* __restrict__ Cout,
        const float* __restrict__ cost, const float* __restrict__ sint){
  __shared__ __align__(1024) char lds[147456];   // 3 x (A 16KB + B 32KB); reused by rope epilogue
  const int tid = threadIdx.x, wid = tid>>6, lane = tid&63, g = lane>>4, c16 = lane&15;
  const int wm = wid>>2, wn = wid&3;
  const int orig = blockIdx.x;
  const int wg = (orig & 7)*32 + (orig >> 3);   // bijective XCD swizzle (grid 256)
  const int bm = wg & 31, bn = wg >> 5;
  const int rowA0 = bm*128, rowB0 = bn*256;
  const char* Ab8 = (const char*)A + (size_t)rowA0*4096;
  const char* Bb8 = (const char*)Bw + (size_t)rowB0*4096;

  f32x4 acc[4][4] = {};

  auto stageA = [&](int t, char* buf, int i){
    int off = i*8192 + tid*16;
    int r = off >> 7;
    int cs = (off & 127) ^ ((r&7)<<4);
    gload16(Ab8 + (size_t)r*4096 + t*128 + cs, buf + i*8192 + wid*1024);
  };
  auto stageB = [&](int t, char* buf, int i){
    int off = i*8192 + tid*16;
    int r = off >> 7;
    int cs = (off & 127) ^ ((r&7)<<4);
    gload16(Bb8 + (size_t)r*4096 + t*128 + cs, buf + 16384 + i*8192 + wid*1024);
  };

  char* b0 = lds;            // tile t   (read)
  char* b1 = lds + 49152;    // tile t+1 (landed/in flight)
  char* b2 = lds + 98304;    // tile t+2 (stage target)

  stageA(0,b0,0); stageA(0,b0,1);
  stageB(0,b0,0); stageB(0,b0,1); stageB(0,b0,2); stageB(0,b0,3);
  stageA(1,b1,0); stageA(1,b1,1);
  stageB(1,b1,0); stageB(1,b1,1); stageB(1,b1,2); stageB(1,b1,3);
  asm volatile("s_waitcnt vmcnt(6)" ::: "memory");
  asm volatile("s_barrier" ::: "memory");

  const int rB[4] = { wn*64 + 0*16 + c16, wn*64 + 1*16 + c16, wn*64 + 2*16 + c16, wn*64 + 3*16 + c16 };
  const int rA[4] = { wm*64 + 0*16 + c16, wm*64 + 1*16 + c16, wm*64 + 2*16 + c16, wm*64 + 3*16 + c16 };

  #pragma unroll 1
  for (int t = 0; t < 32; ++t){
    const char* Abuf = b0;
    const char* Bbuf = b0 + 16384;
    const bool st = (t + 2 < 32);
    bf16x8 bfr[4];

    // ---- ph0: kk=0, mi 0-1 ----
    {
      #pragma unroll
      for (int ni=0;ni<4;ni++)
        bfr[ni] = *(const bf16x8*)(Bbuf + rB[ni]*128 + ((g*16) ^ ((rB[ni]&7)<<4)));
      bf16x8 a0 = *(const bf16x8*)(Abuf + rA[0]*128 + ((g*16) ^ ((rA[0]&7)<<4)));
      bf16x8 a1 = *(const bf16x8*)(Abuf + rA[1]*128 + ((g*16) ^ ((rA[1]&7)<<4)));
      if (st){ stageA(t+2,b2,0); stageA(t+2,b2,1); }
      asm volatile("s_barrier" ::: "memory");
      __builtin_amdgcn_s_setprio(1);
      #pragma unroll
      for (int ni=0;ni<4;ni++){
        acc[0][ni] = __builtin_amdgcn_mfma_f32_16x16x32_bf16(a0, bfr[ni], acc[0][ni],0,0,0);
        acc[1][ni] = __builtin_amdgcn_mfma_f32_16x16x32_bf16(a1, bfr[ni], acc[1][ni],0,0,0);
      }
      __builtin_amdgcn_s_setprio(0);
      asm volatile("s_barrier" ::: "memory");
    }
    // ---- ph1: kk=0, mi 2-3 ----
    {
      bf16x8 a2 = *(const bf16x8*)(Abuf + rA[2]*128 + ((g*16) ^ ((rA[2]&7)<<4)));
      bf16x8 a3 = *(const bf16x8*)(Abuf + rA[3]*128 + ((g*16) ^ ((rA[3]&7)<<4)));
      if (st){ stageB(t+2,b2,0); stageB(t+2,b2,1); }
      asm volatile("s_barrier" ::: "memory");
      __builtin_amdgcn_s_setprio(1);
      #pragma unroll
      for (int ni=0;ni<4;ni++){
        acc[2][ni] = __builtin_amdgcn_mfma_f32_16x16x32_bf16(a2, bfr[ni], acc[2][ni],0,0,0);
        acc[3][ni] = __builtin_amdgcn_mfma_f32_16x16x32_bf16(a3, bfr[ni], acc[3][ni],0,0,0);
      }
      __builtin_amdgcn_s_setprio(0);
      asm volatile("s_barrier" ::: "memory");
    }
    // ---- ph2: kk=1, mi 0-1 ----
    {
      #pragma unroll
      for (int ni=0;ni<4;ni++)
        bfr[ni] = *(const bf16x8*)(Bbuf + rB[ni]*128 + ((64 + g*16) ^ ((rB[ni]&7)<<4)));
      bf16x8 a0 = *(const bf16x8*)(Abuf + rA[0]*128 + ((64 + g*16) ^ ((rA[0]&7)<<4)));
      bf16x8 a1 = *(const bf16x8*)(Abuf + rA[1]*128 + ((64 + g*16) ^ ((rA[1]&7)<<4)));
      if (st){ stageB(t+2,b2,2); }
      asm volatile("s_barrier" ::: "memory");
      __builtin_amdgcn_s_setprio(1);
      #pragma unroll
      for (int ni=0;ni<4;ni++){
        acc[0][ni] = __builtin_amdgcn_mfma_f32_16x16x32_bf16(a0, bfr[ni], acc[0][ni],0,0,0);
        acc[1][ni] = __builtin_amdgcn_mfma_f32_16x16x32_bf16(a1, bfr[ni], acc[1][ni],0,0,0);
      }
      __builtin_amdgcn_s_setprio(0);
      asm volatile("s_barrier" ::: "memory");
    }
    // ---- ph3: kk=1, mi 2-3; tile-boundary vmcnt ----
    {
      bf16x8 a2 = *(const bf16x8*)(Abuf + rA[2]*128 + ((64 + g*16) ^ ((rA[2]&7)<<4)));
      bf16x8 a3 = *(const bf16x8*)(Abuf + rA[3]*128 + ((64 + g*16) ^ ((rA[3]&7)<<4)));
      if (st){ stageB(t+2,b2,3); }
      asm volatile("s_barrier" ::: "memory");
      __builtin_amdgcn_s_setprio(1);
      #pragma unroll
      for (int ni=0;ni<4;ni++){
        acc[2][ni] = __builtin_amdgcn_mfma_f32_16x16x32_bf16(a2, bfr[ni], acc[2][ni],0,0,0);
        acc[3][ni] = __builtin_amdgcn_mfma_f32_16x16x32_bf16(a3, bfr[ni], acc[3][ni],0,0,0);
      }
      __builtin_amdgcn_s_setprio(0);
      if (t + 1 < 32){
        if (st) asm volatile("s_waitcnt vmcnt(6)" ::: "memory");
        else    asm volatile("s_waitcnt vmcnt(0)" ::: "memory");
      }
      asm volatile("s_barrier" ::: "memory");
    }
    char* tmp = b0; b0 = b1; b1 = b2; b2 = tmp;
  }

  if constexpr (MODE == 3 || MODE == 4){
    // ---- fused RoPE epilogue: partner column f^64 exchanged via LDS ----
    float* lf = (float*)lds;                 // [128][260] fp32, biased values
    #pragma unroll
    for (int mi=0;mi<4;mi++){
      #pragma unroll
      for (int ni=0;ni<4;ni++){
        int fl = wn*64 + ni*16 + c16;
        float bv = bias[rowB0 + fl];
        #pragma unroll
        for (int j=0;j<4;j++){
          int ml = wm*64 + mi*16 + g*4 + j;
          lf[ml*260 + fl] = acc[mi][ni][j] + bv;
        }
      }
    }
    __syncthreads();
    #pragma unroll
    for (int mi=0;mi<4;mi++){
      #pragma unroll
      for (int ni=0;ni<4;ni++){
        int fl = wn*64 + ni*16 + c16;
        int f  = rowB0 + fl;
        float bv = bias[f];
        int i  = fl & 63;
        #pragma unroll
        for (int j=0;j<4;j++){
          int ml = wm*64 + mi*16 + g*4 + j;
          int m  = rowA0 + ml;
          int spos = m & (SS-1);
          float c  = cost[spos*64 + i];
          float sn = sint[spos*64 + i];
          float self = acc[mi][ni][j] + bv;
          float part = lf[ml*260 + (fl ^ 64)];
          float v = (fl & 64) ? (self*c + part*sn) : (self*c - part*sn);
          if constexpr (MODE == 3) v *= QSCL;
          ((__hip_bfloat16*)Cout)[(size_t)m*EE + f] = f2bf(v);
        }
      }
    }
  } else {
    #pragma unroll
    for (int mi=0;mi<4;mi++){
      #pragma unroll
      for (int ni=0;ni<4;ni++){
        int f = rowB0 + wn*64 + ni*16 + c16;
        float bv = bias[f];
        #pragma unroll
        for (int j=0;j<4;j++){
          int m = rowA0 + wm*64 + mi*16 + g*4 + j;
          float v = acc[mi][ni][j] + bv;
          if constexpr (MODE == 0) {
            ((__hip_bfloat16*)Cout)[(size_t)m*EE + f] = f2bf(v);
          } else if constexpr (MODE == 1) {
            int b = m >> 11, s = m & (SS-1);
            ((__hip_bfloat16*)Cout)[((size_t)(b*EE + f))*SS + s] = f2bf(v);
          } else {
            ((float*)Cout)[(size_t)m*EE + f] = v;
          }
        }
      }
    }
  }
}

// ---------------- flash attention (causal), swapped-QK^T 32x32x16, 4 waves x 32q ----------------
// R13/R16 structure: phase-skew, conflict-free swizzles, T13 defer, masked-tile skip.
__global__ __launch_bounds__(256, 2) void attn_kernel(const __hip_bfloat16* __restrict__ qg,
    const __hip_bfloat16* __restrict__ kg, const __hip_bfloat16* __restrict__ vtg,
    __hip_bfloat16* __restrict__ og){
  __shared__ short Ks[2][64*128];    // 16KB x2
  __shared__ short Vs3[3][64*128];   // 16KB x3, [64 rows][256B]
  const int tid=threadIdx.x, wid=tid>>6, lane=tid&63;
  const int c32 = lane & 31, hi = lane >> 5;
  const bool skew = (wid >= 2);
  const int id = blockIdx.x;
  const int u = id & 255;
  const int bh = u & 31, pr = u >> 5;
  const int qtile = (id < 256) ? (15 - pr) : pr;
  const int b = bh >> 4, h = bh & 15;
  const int q0 = qtile*128, qw = q0 + wid*32;
  const int qglob = qw + c32;
  const int niter = 2*qtile + 2;

  const char* kb8 = (const char*)(kg + ((size_t)b*SS)*EE + h*DD);
  const char* vb8 = (const char*)(vtg + (size_t)bh*DD*SS);

  const char* qrow = (const char*)(qg + ((size_t)(b*SS + qglob))*EE + h*DD);
  bf16x8 qf[8];
  #pragma unroll
  for (int s=0;s<8;s++) qf[s] = *(const bf16x8*)(qrow + s*32 + hi*16);

  f32x16 pacc[4] = {};
  float mrun = -INFINITY, lrun = 0.f;
  bf16x8 pf[4];

  auto stageK = [&](int kv, short* dst){
    #pragma unroll
    for (int i=0;i<4;i++){
      int base = i*4096 + wid*1024;
      int lb = base + lane*16;
      int r = lb >> 8, cb = lb & 255;
      gload16(kb8 + (size_t)(kv + r)*4096 + (cb ^ ((r&15)<<4)), (char*)dst + base);
    }
  };
  auto stageV = [&](int kv, short* dst){
    #pragma unroll
    for (int i=0;i<4;i++){
      int base = i*4096 + wid*1024;
      int lb = base + lane*16;
      int r = lb >> 8;
      int cs = (lb & 255) ^ ((r&15)<<4);
      int dsrc = r + ((cs >> 7) << 6);
      int kcol = cs & 127;
      gload16(vb8 + (size_t)dsrc*4096 + (size_t)kv*2 + kcol, (char*)dst + base);
    }
  };
  auto pvadd = [&](const short* vbuf){
    const char* Vb = (const char*)vbuf;
    __builtin_amdgcn_s_setprio(1);
    #pragma unroll
    for (int ds=0; ds<4; ds++){
      int d = ds*32 + c32;
      int rr = d & 63;
      int half = (d >> 6) << 7;
      const char* vr = Vb + rr*256;
      int vsw = (rr&15) << 4;
      #pragma unroll
      for (int ks=0; ks<4; ks++){
        bf16x8 vf = *(const bf16x8*)(vr + ((half + ks*32 + hi*16) ^ vsw));
        pacc[ds] = __builtin_amdgcn_mfma_f32_32x32x16_bf16(vf, pf[ks], pacc[ds], 0,0,0);
      }
    }
    __builtin_amdgcn_s_setprio(0);
  };

  short* va = Vs3[0]; short* vbuf = Vs3[1]; short* vc = Vs3[2];
  short* kc = Ks[0];  short* kn = Ks[1];

  stageK(0, kc); stageV(0, vbuf);
  __syncthreads();

  #pragma unroll 1
  for (int it = 0; it < niter; ++it){
    const int kv0 = it*64;
    if (it + 1 < niter){ stageK(kv0+64, kn); stageV(kv0+64, vc); }

    if (skew && it > 0) pvadd(va);

    const bool fullmask = (kv0 > qw + 31);
    if (!fullmask){
      f32x16 st0 = {}, st1 = {};
      {
        const char* Kb = (const char*)kc;
        __builtin_amdgcn_s_setprio(1);
        const int sw0 = (c32&15) << 4;
        #pragma unroll
        for (int s=0;s<8;s++){
          bf16x8 kf0 = *(const bf16x8*)(Kb + c32*256      + ((s*32 + hi*16) ^ sw0));
          bf16x8 kf1 = *(const bf16x8*)(Kb + (32+c32)*256 + ((s*32 + hi*16) ^ sw0));
          st0 = __builtin_amdgcn_mfma_f32_32x32x16_bf16(kf0, qf[s], st0, 0,0,0);
          st1 = __builtin_amdgcn_mfma_f32_32x32x16_bf16(kf1, qf[s], st1, 0,0,0);
        }
        __builtin_amdgcn_s_setprio(0);
      }

      float p[32];
      float vmax = -INFINITY;
      const bool domask = (kv0 + 63 > qw);
      #pragma unroll
      for (int r=0;r<16;r++){
        float v0 = st0[r], v1 = st1[r];
        if (domask){
          int kvo = (r&3) + 8*(r>>2) + 4*hi;
          if (kv0 + kvo > qglob)      v0 = -INFINITY;
          if (kv0 + 32 + kvo > qglob) v1 = -INFINITY;
        }
        p[r] = v0; p[16+r] = v1;
        vmax = fmaxf(vmax, fmaxf(v0, v1));
      }
      vmax = fmaxf(vmax, __shfl_xor(vmax, 32));

      const bool rescale = !__all(vmax <= mrun + 8.0f);
      float mnew = mrun;
      if (rescale){
        mnew = fmaxf(mrun, vmax);
        const float rs = exp2f(mrun - mnew);
        mrun = mnew;
        lrun *= rs;
        #pragma unroll
        for (int ds=0; ds<4; ds++)
          #pragma unroll
          for (int r=0;r<16;r++) pacc[ds][r] *= rs;
      }

      float s0=0.f, s1=0.f, s2=0.f, s3=0.f;
      #pragma unroll
      for (int i=0;i<8;i++){
        p[i]    = exp2f(p[i]    - mnew); s0 += p[i];
        p[8+i]  = exp2f(p[8+i]  - mnew); s1 += p[8+i];
        p[16+i] = exp2f(p[16+i] - mnew); s2 += p[16+i];
        p[24+i] = exp2f(p[24+i] - mnew); s3 += p[24+i];
      }
      float ps = (s0 + s1) + (s2 + s3);
      ps += __shfl_xor(ps, 32);
      lrun += ps;

      unsigned w[2][4][2];
      #pragma unroll
      for (int T=0;T<2;T++)
        #pragma unroll
        for (int m=0;m<4;m++)
          #pragma unroll
          for (int uu=0;uu<2;uu++)
            w[T][m][uu] = pk2(p[T*16 + 4*m + 2*uu], p[T*16 + 4*m + 2*uu + 1]);

      #pragma unroll
      for (int ks=0; ks<4; ks++){
        int T = ks>>1, lo2 = (ks&1)*2;
        unsigned o0 = hi ? w[T][lo2+1][0] : w[T][lo2+0][0];
        unsigned o1 = hi ? w[T][lo2+1][1] : w[T][lo2+0][1];
        unsigned x0 = hi ? w[T][lo2+0][0] : w[T][lo2+1][0];
        unsigned x1 = hi ? w[T][lo2+0][1] : w[T][lo2+1][1];
        unsigned r0 = (unsigned)__shfl_xor((int)x0, 32);
        unsigned r1 = (unsigned)__shfl_xor((int)x1, 32);
        union { u32x4 u4; bf16x8 h8; } cvt;
        cvt.u4[0] = hi ? r0 : o0;
        cvt.u4[1] = hi ? r1 : o1;
        cvt.u4[2] = hi ? o0 : r0;
        cvt.u4[3] = hi ? o1 : r1;
        pf[ks] = cvt.h8;
      }

      if (!skew) pvadd(vbuf);
    }

    __syncthreads();
    short* t = va; va = vbuf; vbuf = vc; vc = t;
    short* tk = kc; kc = kn; kn = tk;
  }

  if (skew) pvadd(va);

  const float invl = 1.0f / lrun;
  char* orow = (char*)(og + ((size_t)(b*SS + qglob))*EE + h*DD);
  #pragma unroll
  for (int ds=0; ds<4; ds++){
    #pragma unroll
    for (int m=0;m<4;m++){
      int d0 = ds*32 + 8*m + 4*hi;
      short4 s4;
      s4.x = f2bs(pacc[ds][4*m+0]*invl);
      s4.y = f2bs(pacc[ds][4*m+1]*invl);
      s4.z = f2bs(pacc[ds][4*m+2]*invl);
      s4.w = f2bs(pacc[ds][4*m+3]*invl);
      *(short4*)(orow + d0*2) = s4;
    }
  }
}

extern "C" void kernel_launch(void* const* d_in, const int* in_sizes, int n_in,
                              void* d_out, int out_size, void* d_ws, size_t ws_size,
                              hipStream_t stream){
  const float* x  = (const float*)d_in[0];
  const float* Wq = (const float*)d_in[1];
  const float* bq = (const float*)d_in[2];
  const float* Wk = (const float*)d_in[3];
  const float* bk = (const float*)d_in[4];
  const float* Wv = (const float*)d_in[5];
  const float* bv = (const float*)d_in[6];
  const float* Wp = (const float*)d_in[7];
  const float* bp = (const float*)d_in[8];
  float* out = (float*)d_out;

  char* ws = (char*)d_ws;
  size_t off = 0;
  auto alloc = [&](size_t bytes){ void* p = ws + off; off += (bytes + 255) & ~(size_t)255; return p; };
  const size_t nx = (size_t)MM*EE;
  const size_t nw = (size_t)EE*EE;
  __hip_bfloat16* xb  = (__hip_bfloat16*)alloc(nx*2);
  __hip_bfloat16* wqb = (__hip_bfloat16*)alloc(nw*2);
  __hip_bfloat16* wkb = (__hip_bfloat16*)alloc(nw*2);
  __hip_bfloat16* wvb = (__hip_bfloat16*)alloc(nw*2);
  __hip_bfloat16* wpb = (__hip_bfloat16*)alloc(nw*2);
  __hip_bfloat16* qb  = (__hip_bfloat16*)alloc(nx*2);
  __hip_bfloat16* kb  = (__hip_bfloat16*)alloc(nx*2);
  __hip_bfloat16* vtb = (__hip_bfloat16*)alloc(nx*2);
  __hip_bfloat16* ob  = (__hip_bfloat16*)alloc(nx*2);
  float* cost = (float*)alloc((size_t)SS*64*4);
  float* sint = (float*)alloc((size_t)SS*64*4);

  P6 p6{x, Wq, Wk, Wv, Wp, xb, wqb, wkb, wvb, wpb, cost, sint};
  prep_kernel<<<dim3(4096, 6), 256, 0, stream>>>(p6);

  gemm256<3><<<256, 512, 0, stream>>>(xb, wqb, bq, qb,  cost, sint);   // q + RoPE + QSCL
  gemm256<4><<<256, 512, 0, stream>>>(xb, wkb, bk, kb,  cost, sint);   // k + RoPE
  gemm256<1><<<256, 512, 0, stream>>>(xb, wvb, bv, vtb, nullptr, nullptr);

  attn_kernel<<<dim3(512), 256, 0, stream>>>(qb, kb, vtb, ob);

  gemm256<2><<<256, 512, 0, stream>>>(ob, wpb, bp, out, nullptr, nullptr);
}

// Round 21
// 258.551 us; speedup vs baseline: 1.0681x; 1.0027x over previous
//
#include <hip/hip_runtime.h>
#include <hip/hip_bf16.h>
#include <math.h>

#define BB 2
#define SS 2048
#define EE 2048
#define HH 16
#define DD 128
#define MM (BB*SS)

typedef __attribute__((ext_vector_type(8))) short bf16x8;
typedef __attribute__((ext_vector_type(4))) float f32x4;
typedef __attribute__((ext_vector_type(16))) float f32x16;
typedef __attribute__((ext_vector_type(4))) unsigned u32x4;

__device__ inline float bf2f(const __hip_bfloat16 h){ return __bfloat162float(h); }
__device__ inline __hip_bfloat16 f2bf(float f){ return __float2bfloat16(f); }
__device__ inline short f2bs(float f){
  union { __hip_bfloat16 h; short s; } u; u.h = __float2bfloat16(f); return u.s;
}
__device__ inline unsigned pk2(float a, float b){
  union { __hip_bfloat162 h2; unsigned u; } x;
  x.h2 = __float22bfloat162_rn(float2{a,b}); return x.u;   // low half = a
}

__device__ inline void gload16(const void* g, void* l){
  __builtin_amdgcn_global_load_lds((const __attribute__((address_space(1))) void*)g,
      (__attribute__((address_space(3))) void*)l, 16, 0, 0);
}

// 1/sqrt(128) * log2(e): folded into Q during its GEMM-epilogue RoPE
#define QSCL 0.12754614533018515f

// ---------------- prep: fp32->bf16 convert (x + 4 weights) AND rope tables, one launch ----------------
struct P6 { const float* s0; const float* s1; const float* s2; const float* s3; const float* s4;
            __hip_bfloat16* d0; __hip_bfloat16* d1; __hip_bfloat16* d2; __hip_bfloat16* d3; __hip_bfloat16* d4;
            float* cost; float* sint; };
__global__ void prep_kernel(P6 p){
  int w = blockIdx.y;
  int bid = blockIdx.x, t = threadIdx.x;
  if (w == 5){
    int idx = bid*256 + t;           // SS*64 = 131072 = 512 blocks
    if (bid >= 512) return;
    int s = idx >> 6, i = idx & 63;
    double inv = exp(-log(10000.0) * (double)i / 64.0);
    double f = (double)s * inv;
    p.cost[idx] = (float)cos(f);
    p.sint[idx] = (float)sin(f);
    return;
  }
  if (w == 0){
    const float4* in = (const float4*)p.s0;
    short4* out = (short4*)p.d0;
    #pragma unroll
    for (int rep=0; rep<2; rep++){
      int i = (bid*2 + rep)*256 + t;     // covers 2M float4
      float4 v = in[i];
      union { short4 s4; short s[4]; } u;
      u.s[0]=f2bs(v.x); u.s[1]=f2bs(v.y); u.s[2]=f2bs(v.z); u.s[3]=f2bs(v.w);
      out[i] = u.s4;
    }
    return;
  }
  const float* in = w==1 ? p.s1 : w==2 ? p.s2 : w==3 ? p.s3 : p.s4;
  __hip_bfloat16* out = w==1 ? p.d1 : w==2 ? p.d2 : w==3 ? p.d3 : p.d4;
  int i = bid*256 + t;                   // covers 1M float4
  float4 v = ((const float4*)in)[i];
  union { short4 s4; short s[4]; } u;
  u.s[0]=f2bs(v.x); u.s[1]=f2bs(v.y); u.s[2]=f2bs(v.z); u.s[3]=f2bs(v.w);
  ((short4*)out)[i] = u.s4;
}

// ---------------- bf16 GEMM, 128x256 tile, BK=64, 8 waves, 4-phase pipeline ----------------
// MODE 0: bf16 C[m*EE+f]; MODE 1: bf16 vt[(b*EE+f)*SS+s]; MODE 2: fp32 C;
// MODE 3: bf16 C with fused RoPE + QSCL (q); MODE 4: bf16 C with fused RoPE (k).
template<int MODE>
__global__ __launch_bounds__(512) void gemm256(const __hip_bfloat16* __restrict__ A,
        const __hip_bfloat16* __restrict__ Bw, const float* __restrict__ bias,
        void* __restrict__ Cout,
        const float* __restrict__ cost, const float* __restrict__ sint){
  __shared__ __align__(1024) char lds[147456];   // 3 x (A 16KB + B 32KB); reused by rope epilogue
  const int tid = threadIdx.x, wid = tid>>6, lane = tid&63, g = lane>>4, c16 = lane&15;
  const int wm = wid>>2, wn = wid&3;
  const int orig = blockIdx.x;
  const int wg = (orig & 7)*32 + (orig >> 3);   // bijective XCD swizzle (grid 256)
  const int bm = wg & 31, bn = wg >> 5;
  const int rowA0 = bm*128, rowB0 = bn*256;
  const char* Ab8 = (const char*)A + (size_t)rowA0*4096;
  const char* Bb8 = (const char*)Bw + (size_t)rowB0*4096;

  f32x4 acc[4][4] = {};

  auto stageA = [&](int t, char* buf, int i){
    int off = i*8192 + tid*16;
    int r = off >> 7;
    int cs = (off & 127) ^ ((r&7)<<4);
    gload16(Ab8 + (size_t)r*4096 + t*128 + cs, buf + i*8192 + wid*1024);
  };
  auto stageB = [&](int t, char* buf, int i){
    int off = i*8192 + tid*16;
    int r = off >> 7;
    int cs = (off & 127) ^ ((r&7)<<4);
    gload16(Bb8 + (size_t)r*4096 + t*128 + cs, buf + 16384 + i*8192 + wid*1024);
  };

  char* b0 = lds;            // tile t   (read)
  char* b1 = lds + 49152;    // tile t+1 (landed/in flight)
  char* b2 = lds + 98304;    // tile t+2 (stage target)

  stageA(0,b0,0); stageA(0,b0,1);
  stageB(0,b0,0); stageB(0,b0,1); stageB(0,b0,2); stageB(0,b0,3);
  stageA(1,b1,0); stageA(1,b1,1);
  stageB(1,b1,0); stageB(1,b1,1); stageB(1,b1,2); stageB(1,b1,3);
  asm volatile("s_waitcnt vmcnt(6)" ::: "memory");
  asm volatile("s_barrier" ::: "memory");

  const int rB[4] = { wn*64 + 0*16 + c16, wn*64 + 1*16 + c16, wn*64 + 2*16 + c16, wn*64 + 3*16 + c16 };
  const int rA[4] = { wm*64 + 0*16 + c16, wm*64 + 1*16 + c16, wm*64 + 2*16 + c16, wm*64 + 3*16 + c16 };

  #pragma unroll 1
  for (int t = 0; t < 32; ++t){
    const char* Abuf = b0;
    const char* Bbuf = b0 + 16384;
    const bool st = (t + 2 < 32);
    bf16x8 bfr[4];

    // ---- ph0: kk=0, mi 0-1 ----
    {
      #pragma unroll
      for (int ni=0;ni<4;ni++)
        bfr[ni] = *(const bf16x8*)(Bbuf + rB[ni]*128 + ((g*16) ^ ((rB[ni]&7)<<4)));
      bf16x8 a0 = *(const bf16x8*)(Abuf + rA[0]*128 + ((g*16) ^ ((rA[0]&7)<<4)));
      bf16x8 a1 = *(const bf16x8*)(Abuf + rA[1]*128 + ((g*16) ^ ((rA[1]&7)<<4)));
      if (st){ stageA(t+2,b2,0); stageA(t+2,b2,1); }
      asm volatile("s_barrier" ::: "memory");
      __builtin_amdgcn_s_setprio(1);
      #pragma unroll
      for (int ni=0;ni<4;ni++){
        acc[0][ni] = __builtin_amdgcn_mfma_f32_16x16x32_bf16(a0, bfr[ni], acc[0][ni],0,0,0);
        acc[1][ni] = __builtin_amdgcn_mfma_f32_16x16x32_bf16(a1, bfr[ni], acc[1][ni],0,0,0);
      }
      __builtin_amdgcn_s_setprio(0);
      asm volatile("s_barrier" ::: "memory");
    }
    // ---- ph1: kk=0, mi 2-3 ----
    {
      bf16x8 a2 = *(const bf16x8*)(Abuf + rA[2]*128 + ((g*16) ^ ((rA[2]&7)<<4)));
      bf16x8 a3 = *(const bf16x8*)(Abuf + rA[3]*128 + ((g*16) ^ ((rA[3]&7)<<4)));
      if (st){ stageB(t+2,b2,0); stageB(t+2,b2,1); }
      asm volatile("s_barrier" ::: "memory");
      __builtin_amdgcn_s_setprio(1);
      #pragma unroll
      for (int ni=0;ni<4;ni++){
        acc[2][ni] = __builtin_amdgcn_mfma_f32_16x16x32_bf16(a2, bfr[ni], acc[2][ni],0,0,0);
        acc[3][ni] = __builtin_amdgcn_mfma_f32_16x16x32_bf16(a3, bfr[ni], acc[3][ni],0,0,0);
      }
      __builtin_amdgcn_s_setprio(0);
      asm volatile("s_barrier" ::: "memory");
    }
    // ---- ph2: kk=1, mi 0-1 ----
    {
      #pragma unroll
      for (int ni=0;ni<4;ni++)
        bfr[ni] = *(const bf16x8*)(Bbuf + rB[ni]*128 + ((64 + g*16) ^ ((rB[ni]&7)<<4)));
      bf16x8 a0 = *(const bf16x8*)(Abuf + rA[0]*128 + ((64 + g*16) ^ ((rA[0]&7)<<4)));
      bf16x8 a1 = *(const bf16x8*)(Abuf + rA[1]*128 + ((64 + g*16) ^ ((rA[1]&7)<<4)));
      if (st){ stageB(t+2,b2,2); }
      asm volatile("s_barrier" ::: "memory");
      __builtin_amdgcn_s_setprio(1);
      #pragma unroll
      for (int ni=0;ni<4;ni++){
        acc[0][ni] = __builtin_amdgcn_mfma_f32_16x16x32_bf16(a0, bfr[ni], acc[0][ni],0,0,0);
        acc[1][ni] = __builtin_amdgcn_mfma_f32_16x16x32_bf16(a1, bfr[ni], acc[1][ni],0,0,0);
      }
      __builtin_amdgcn_s_setprio(0);
      asm volatile("s_barrier" ::: "memory");
    }
    // ---- ph3: kk=1, mi 2-3; tile-boundary vmcnt ----
    {
      bf16x8 a2 = *(const bf16x8*)(Abuf + rA[2]*128 + ((64 + g*16) ^ ((rA[2]&7)<<4)));
      bf16x8 a3 = *(const bf16x8*)(Abuf + rA[3]*128 + ((64 + g*16) ^ ((rA[3]&7)<<4)));
      if (st){ stageB(t+2,b2,3); }
      asm volatile("s_barrier" ::: "memory");
      __builtin_amdgcn_s_setprio(1);
      #pragma unroll
      for (int ni=0;ni<4;ni++){
        acc[2][ni] = __builtin_amdgcn_mfma_f32_16x16x32_bf16(a2, bfr[ni], acc[2][ni],0,0,0);
        acc[3][ni] = __builtin_amdgcn_mfma_f32_16x16x32_bf16(a3, bfr[ni], acc[3][ni],0,0,0);
      }
      __builtin_amdgcn_s_setprio(0);
      if (t + 1 < 32){
        if (st) asm volatile("s_waitcnt vmcnt(6)" ::: "memory");
        else    asm volatile("s_waitcnt vmcnt(0)" ::: "memory");
      }
      asm volatile("s_barrier" ::: "memory");
    }
    char* tmp = b0; b0 = b1; b1 = b2; b2 = tmp;
  }

  if constexpr (MODE == 3 || MODE == 4){
    // ---- fused RoPE epilogue: partner column f^64 exchanged via LDS ----
    float* lf = (float*)lds;                 // [128][260] fp32, biased values
    #pragma unroll
    for (int mi=0;mi<4;mi++){
      #pragma unroll
      for (int ni=0;ni<4;ni++){
        int fl = wn*64 + ni*16 + c16;
        float bv = bias[rowB0 + fl];
        #pragma unroll
        for (int j=0;j<4;j++){
          int ml = wm*64 + mi*16 + g*4 + j;
          lf[ml*260 + fl] = acc[mi][ni][j] + bv;
        }
      }
    }
    __syncthreads();
    #pragma unroll
    for (int mi=0;mi<4;mi++){
      #pragma unroll
      for (int ni=0;ni<4;ni++){
        int fl = wn*64 + ni*16 + c16;
        int f  = rowB0 + fl;
        float bv = bias[f];
        int i  = fl & 63;
        #pragma unroll
        for (int j=0;j<4;j++){
          int ml = wm*64 + mi*16 + g*4 + j;
          int m  = rowA0 + ml;
          int spos = m & (SS-1);
          float c  = cost[spos*64 + i];
          float sn = sint[spos*64 + i];
          float self = acc[mi][ni][j] + bv;
          float part = lf[ml*260 + (fl ^ 64)];
          float v = (fl & 64) ? (self*c + part*sn) : (self*c - part*sn);
          if constexpr (MODE == 3) v *= QSCL;
          ((__hip_bfloat16*)Cout)[(size_t)m*EE + f] = f2bf(v);
        }
      }
    }
  } else {
    #pragma unroll
    for (int mi=0;mi<4;mi++){
      #pragma unroll
      for (int ni=0;ni<4;ni++){
        int f = rowB0 + wn*64 + ni*16 + c16;
        float bv = bias[f];
        #pragma unroll
        for (int j=0;j<4;j++){
          int m = rowA0 + wm*64 + mi*16 + g*4 + j;
          float v = acc[mi][ni][j] + bv;
          if constexpr (MODE == 0) {
            ((__hip_bfloat16*)Cout)[(size_t)m*EE + f] = f2bf(v);
          } else if constexpr (MODE == 1) {
            int b = m >> 11, s = m & (SS-1);
            ((__hip_bfloat16*)Cout)[((size_t)(b*EE + f))*SS + s] = f2bf(v);
          } else {
            ((float*)Cout)[(size_t)m*EE + f] = v;
          }
        }
      }
    }
  }
}

// ---------------- flash attention (causal), swapped-QK^T 32x32x16, 4 waves x 32q ----------------
// R20 structure + QK^T split into 4 independent MFMA chains (was 2x8-deep; now
// 4x4-deep, combined with one vector add) to cover MFMA chain latency.
__global__ __launch_bounds__(256, 2) void attn_kernel(const __hip_bfloat16* __restrict__ qg,
    const __hip_bfloat16* __restrict__ kg, const __hip_bfloat16* __restrict__ vtg,
    __hip_bfloat16* __restrict__ og){
  __shared__ short Ks[2][64*128];    // 16KB x2
  __shared__ short Vs3[3][64*128];   // 16KB x3, [64 rows][256B]
  const int tid=threadIdx.x, wid=tid>>6, lane=tid&63;
  const int c32 = lane & 31, hi = lane >> 5;
  const bool skew = (wid >= 2);
  const int id = blockIdx.x;
  const int u = id & 255;
  const int bh = u & 31, pr = u >> 5;
  const int qtile = (id < 256) ? (15 - pr) : pr;
  const int b = bh >> 4, h = bh & 15;
  const int q0 = qtile*128, qw = q0 + wid*32;
  const int qglob = qw + c32;
  const int niter = 2*qtile + 2;

  const char* kb8 = (const char*)(kg + ((size_t)b*SS)*EE + h*DD);
  const char* vb8 = (const char*)(vtg + (size_t)bh*DD*SS);

  const char* qrow = (const char*)(qg + ((size_t)(b*SS + qglob))*EE + h*DD);
  bf16x8 qf[8];
  #pragma unroll
  for (int s=0;s<8;s++) qf[s] = *(const bf16x8*)(qrow + s*32 + hi*16);

  f32x16 pacc[4] = {};
  float mrun = -INFINITY, lrun = 0.f;
  bf16x8 pf[4];

  auto stageK = [&](int kv, short* dst){
    #pragma unroll
    for (int i=0;i<4;i++){
      int base = i*4096 + wid*1024;
      int lb = base + lane*16;
      int r = lb >> 8, cb = lb & 255;
      gload16(kb8 + (size_t)(kv + r)*4096 + (cb ^ ((r&15)<<4)), (char*)dst + base);
    }
  };
  auto stageV = [&](int kv, short* dst){
    #pragma unroll
    for (int i=0;i<4;i++){
      int base = i*4096 + wid*1024;
      int lb = base + lane*16;
      int r = lb >> 8;
      int cs = (lb & 255) ^ ((r&15)<<4);
      int dsrc = r + ((cs >> 7) << 6);
      int kcol = cs & 127;
      gload16(vb8 + (size_t)dsrc*4096 + (size_t)kv*2 + kcol, (char*)dst + base);
    }
  };
  auto pvadd = [&](const short* vbuf){
    const char* Vb = (const char*)vbuf;
    __builtin_amdgcn_s_setprio(1);
    #pragma unroll
    for (int ds=0; ds<4; ds++){
      int d = ds*32 + c32;
      int rr = d & 63;
      int half = (d >> 6) << 7;
      const char* vr = Vb + rr*256;
      int vsw = (rr&15) << 4;
      #pragma unroll
      for (int ks=0; ks<4; ks++){
        bf16x8 vf = *(const bf16x8*)(vr + ((half + ks*32 + hi*16) ^ vsw));
        pacc[ds] = __builtin_amdgcn_mfma_f32_32x32x16_bf16(vf, pf[ks], pacc[ds], 0,0,0);
      }
    }
    __builtin_amdgcn_s_setprio(0);
  };

  short* va = Vs3[0]; short* vbuf = Vs3[1]; short* vc = Vs3[2];
  short* kc = Ks[0];  short* kn = Ks[1];

  stageK(0, kc); stageV(0, vbuf);
  __syncthreads();

  #pragma unroll 1
  for (int it = 0; it < niter; ++it){
    const int kv0 = it*64;
    if (it + 1 < niter){ stageK(kv0+64, kn); stageV(kv0+64, vc); }

    if (skew && it > 0) pvadd(va);

    const bool fullmask = (kv0 > qw + 31);
    if (!fullmask){
      f32x16 st0, st1;
      {
        const char* Kb = (const char*)kc;
        __builtin_amdgcn_s_setprio(1);
        const int sw0 = (c32&15) << 4;
        f32x16 e0 = {}, e1 = {}, o0 = {}, o1 = {};   // 4 independent chains, 4 deep
        #pragma unroll
        for (int s=0;s<4;s++){
          bf16x8 kf0a = *(const bf16x8*)(Kb + c32*256      + ((s*32 + hi*16) ^ sw0));
          bf16x8 kf1a = *(const bf16x8*)(Kb + (32+c32)*256 + ((s*32 + hi*16) ^ sw0));
          bf16x8 kf0b = *(const bf16x8*)(Kb + c32*256      + (((s+4)*32 + hi*16) ^ sw0));
          bf16x8 kf1b = *(const bf16x8*)(Kb + (32+c32)*256 + (((s+4)*32 + hi*16) ^ sw0));
          e0 = __builtin_amdgcn_mfma_f32_32x32x16_bf16(kf0a, qf[s],   e0, 0,0,0);
          e1 = __builtin_amdgcn_mfma_f32_32x32x16_bf16(kf1a, qf[s],   e1, 0,0,0);
          o0 = __builtin_amdgcn_mfma_f32_32x32x16_bf16(kf0b, qf[s+4], o0, 0,0,0);
          o1 = __builtin_amdgcn_mfma_f32_32x32x16_bf16(kf1b, qf[s+4], o1, 0,0,0);
        }
        __builtin_amdgcn_s_setprio(0);
        st0 = e0 + o0;
        st1 = e1 + o1;
      }

      float p[32];
      float vmax = -INFINITY;
      const bool domask = (kv0 + 63 > qw);
      #pragma unroll
      for (int r=0;r<16;r++){
        float v0 = st0[r], v1 = st1[r];
        if (domask){
          int kvo = (r&3) + 8*(r>>2) + 4*hi;
          if (kv0 + kvo > qglob)      v0 = -INFINITY;
          if (kv0 + 32 + kvo > qglob) v1 = -INFINITY;
        }
        p[r] = v0; p[16+r] = v1;
        vmax = fmaxf(vmax, fmaxf(v0, v1));
      }
      vmax = fmaxf(vmax, __shfl_xor(vmax, 32));

      const bool rescale = !__all(vmax <= mrun + 8.0f);
      float mnew = mrun;
      if (rescale){
        mnew = fmaxf(mrun, vmax);
        const float rs = exp2f(mrun - mnew);
        mrun = mnew;
        lrun *= rs;
        #pragma unroll
        for (int ds=0; ds<4; ds++)
          #pragma unroll
          for (int r=0;r<16;r++) pacc[ds][r] *= rs;
      }

      float s0=0.f, s1=0.f, s2=0.f, s3=0.f;
      #pragma unroll
      for (int i=0;i<8;i++){
        p[i]    = exp2f(p[i]    - mnew); s0 += p[i];
        p[8+i]  = exp2f(p[8+i]  - mnew); s1 += p[8+i];
        p[16+i] = exp2f(p[16+i] - mnew); s2 += p[16+i];
        p[24+i] = exp2f(p[24+i] - mnew); s3 += p[24+i];
      }
      float ps = (s0 + s1) + (s2 + s3);
      ps += __shfl_xor(ps, 32);
      lrun += ps;

      unsigned w[2][4][2];
      #pragma unroll
      for (int T=0;T<2;T++)
        #pragma unroll
        for (int m=0;m<4;m++)
          #pragma unroll
          for (int uu=0;uu<2;uu++)
            w[T][m][uu] = pk2(p[T*16 + 4*m + 2*uu], p[T*16 + 4*m + 2*uu + 1]);

      #pragma unroll
      for (int ks=0; ks<4; ks++){
        int T = ks>>1, lo2 = (ks&1)*2;
        unsigned o0 = hi ? w[T][lo2+1][0] : w[T][lo2+0][0];
        unsigned o1 = hi ? w[T][lo2+1][1] : w[T][lo2+0][1];
        unsigned x0 = hi ? w[T][lo2+0][0] : w[T][lo2+1][0];
        unsigned x1 = hi ? w[T][lo2+0][1] : w[T][lo2+1][1];
        unsigned r0 = (unsigned)__shfl_xor((int)x0, 32);
        unsigned r1 = (unsigned)__shfl_xor((int)x1, 32);
        union { u32x4 u4; bf16x8 h8; } cvt;
        cvt.u4[0] = hi ? r0 : o0;
        cvt.u4[1] = hi ? r1 : o1;
        cvt.u4[2] = hi ? o0 : r0;
        cvt.u4[3] = hi ? o1 : r1;
        pf[ks] = cvt.h8;
      }

      if (!skew) pvadd(vbuf);
    }

    __syncthreads();
    short* t = va; va = vbuf; vbuf = vc; vc = t;
    short* tk = kc; kc = kn; kn = tk;
  }

  if (skew) pvadd(va);

  const float invl = 1.0f / lrun;
  char* orow = (char*)(og + ((size_t)(b*SS + qglob))*EE + h*DD);
  #pragma unroll
  for (int ds=0; ds<4; ds++){
    #pragma unroll
    for (int m=0;m<4;m++){
      int d0 = ds*32 + 8*m + 4*hi;
      short4 s4;
      s4.x = f2bs(pacc[ds][4*m+0]*invl);
      s4.y = f2bs(pacc[ds][4*m+1]*invl);
      s4.z = f2bs(pacc[ds][4*m+2]*invl);
      s4.w = f2bs(pacc[ds][4*m+3]*invl);
      *(short4*)(orow + d0*2) = s4;
    }
  }
}

extern "C" void kernel_launch(void* const* d_in, const int* in_sizes, int n_in,
                              void* d_out, int out_size, void* d_ws, size_t ws_size,
                              hipStream_t stream){
  const float* x  = (const float*)d_in[0];
  const float* Wq = (const float*)d_in[1];
  const float* bq = (const float*)d_in[2];
  const float* Wk = (const float*)d_in[3];
  const float* bk = (const float*)d_in[4];
  const float* Wv = (const float*)d_in[5];
  const float* bv = (const float*)d_in[6];
  const float* Wp = (const float*)d_in[7];
  const float* bp = (const float*)d_in[8];
  float* out = (float*)d_out;

  char* ws = (char*)d_ws;
  size_t off = 0;
  auto alloc = [&](size_t bytes){ void* p = ws + off; off += (bytes + 255) & ~(size_t)255; return p; };
  const size_t nx = (size_t)MM*EE;
  const size_t nw = (size_t)EE*EE;
  __hip_bfloat16* xb  = (__hip_bfloat16*)alloc(nx*2);
  __hip_bfloat16* wqb = (__hip_bfloat16*)alloc(nw*2);
  __hip_bfloat16* wkb = (__hip_bfloat16*)alloc(nw*2);
  __hip_bfloat16* wvb = (__hip_bfloat16*)alloc(nw*2);
  __hip_bfloat16* wpb = (__hip_bfloat16*)alloc(nw*2);
  __hip_bfloat16* qb  = (__hip_bfloat16*)alloc(nx*2);
  __hip_bfloat16* kb  = (__hip_bfloat16*)alloc(nx*2);
  __hip_bfloat16* vtb = (__hip_bfloat16*)alloc(nx*2);
  __hip_bfloat16* ob  = (__hip_bfloat16*)alloc(nx*2);
  float* cost = (float*)alloc((size_t)SS*64*4);
  float* sint = (float*)alloc((size_t)SS*64*4);

  P6 p6{x, Wq, Wk, Wv, Wp, xb, wqb, wkb, wvb, wpb, cost, sint};
  prep_kernel<<<dim3(4096, 6), 256, 0, stream>>>(p6);

  gemm256<3><<<256, 512, 0, stream>>>(xb, wqb, bq, qb,  cost, sint);   // q + RoPE + QSCL
  gemm256<4><<<256, 512, 0, stream>>>(xb, wkb, bk, kb,  cost, sint);   // k + RoPE
  gemm256<1><<<256, 512, 0, stream>>>(xb, wvb, bv, vtb, nullptr, nullptr);

  attn_kernel<<<dim3(512), 256, 0, stream>>>(qb, kb, vtb, ob);

  gemm256<2><<<256, 512, 0, stream>>>(ob, wpb, bp, out, nullptr, nullptr);
}